// Round 1
// baseline (1152.423 us; speedup 1.0000x reference)
//
#include <hip/hip_runtime.h>

// ---------------- problem constants ----------------
constexpr int B_   = 8;
constexpr int L_   = 128;
constexpr int D_   = 512;
constexpr int MAW_ = 8;
constexpr int SWF_ = 20;
constexpr int FF_  = 512;
constexpr int R_   = 19;
constexpr int G_   = 4;
constexpr int SPAN_ = 3 * D_ + SWF_;   // 1556
constexpr int S1_   = SPAN_ + 1;       // 1557
constexpr int S_    = L_ * MAW_;       // 1024 spans / batch
constexpr int NS_   = B_ * S_;         // 8192 spans total
constexpr int NP_   = B_ * G_;         // 32 predicates
constexpr int TM_   = R_ * S1_;        // 29583 rows of biaffine_w
constexpr int M8_   = NS_ * G_;        // 32768 pairwise rows

// ---------------- workspace layout (float offsets) ----------------
constexpr size_t OFF_HS_ARG = 0;               // 6 x 1024x512 projections
constexpr size_t OFF_HE_ARG = 524288;
constexpr size_t OFF_HH_ARG = 1048576;
constexpr size_t OFF_HS_SRL = 1572864;
constexpr size_t OFF_HE_SRL = 2097152;
constexpr size_t OFF_HH_SRL = 2621440;
constexpr size_t OFF_PH_ARG = 3145728;         // 8 x 129 x 512 prefix
constexpr size_t OFF_PH_SRL = 3674112;
constexpr size_t OFF_P_SRL  = 4202496;         // 32 x 512
constexpr size_t OFF_PSCORE = 4218880;         // 32
constexpr size_t OFF_PRED1  = 4218912;         // 32 x 1557
constexpr size_t OFF_WD_ARG = 4268736;         // 8 x 512
constexpr size_t OFF_WD_SRL = 4272832;         // 8 x 512
constexpr size_t OFF_T      = 4276928;         // 32 x 29583  [p][r*1557+i]
constexpr size_t OFF_MS     = 5223584;         // 608 x 128
constexpr size_t OFF_ME     = 5301408;         // 608 x 128
constexpr size_t OFF_MHP    = 5379232;         // 608 x 129
constexpr size_t OFF_MW     = 5457664;         // 608 x 8
constexpr size_t OFF_TC     = 5462528;         // 608
constexpr size_t OFF_HARG   = 5463136;         // 8192 x 512
constexpr size_t OFF_ASRL   = 9657440;         // 8192 x 512
constexpr size_t OFF_ARGS   = 13851744;        // 8192
// total = 13,859,936 floats = 55.4 MB

// =====================================================================
// K1: six per-token projections  Hx = hidden(1024x512) @ W(512x512)
// one GEMM with N=3072; tile 64x128, KC=16
// =====================================================================
__global__ __launch_bounds__(256) void k1_proj(const float* __restrict__ hidden,
                                               const float* __restrict__ arg_w0,
                                               const float* __restrict__ srl_w0,
                                               float* __restrict__ ws) {
  __shared__ float As[16][68];
  __shared__ float Bs[16][132];
  const int tid = threadIdx.x;
  const int m0 = blockIdx.x * 64;
  const int by = blockIdx.y;
  const int j = by >> 2;               // which projection 0..5
  const int c0 = (by & 3) * 128;       // col offset within projection
  const int rowoffs[3] = {0, 512, 1044};
  const float* W = (j < 3) ? (arg_w0 + (size_t)rowoffs[j] * FF_)
                           : (srl_w0 + (size_t)rowoffs[j - 3] * FF_);
  float* C = ws + (size_t)j * 524288;

  const int tx = tid & 15, ty = tid >> 4;
  float acc[4][8];
#pragma unroll
  for (int i = 0; i < 4; ++i)
#pragma unroll
    for (int jj = 0; jj < 8; ++jj) acc[i][jj] = 0.f;

  const int mlA = tid >> 2, kqA = (tid & 3) * 4;
  const int n4B = (tid & 31) * 4, krB = tid >> 5;

  for (int kc = 0; kc < 32; ++kc) {
    // stage A (transposed into LDS)
    float4 av = *(const float4*)&hidden[(size_t)(m0 + mlA) * D_ + kc * 16 + kqA];
    As[kqA + 0][mlA] = av.x; As[kqA + 1][mlA] = av.y;
    As[kqA + 2][mlA] = av.z; As[kqA + 3][mlA] = av.w;
    // stage B
#pragma unroll
    for (int it = 0; it < 2; ++it) {
      int k = krB + it * 8;
      *(float4*)&Bs[k][n4B] = *(const float4*)&W[(size_t)(kc * 16 + k) * FF_ + c0 + n4B];
    }
    __syncthreads();
#pragma unroll
    for (int kk = 0; kk < 16; ++kk) {
      float4 a  = *(const float4*)&As[kk][ty * 4];
      float4 b0 = *(const float4*)&Bs[kk][tx * 8];
      float4 b1 = *(const float4*)&Bs[kk][tx * 8 + 4];
      float ar[4] = {a.x, a.y, a.z, a.w};
      float br[8] = {b0.x, b0.y, b0.z, b0.w, b1.x, b1.y, b1.z, b1.w};
#pragma unroll
      for (int i = 0; i < 4; ++i)
#pragma unroll
        for (int jj = 0; jj < 8; ++jj) acc[i][jj] += ar[i] * br[jj];
    }
    __syncthreads();
  }
#pragma unroll
  for (int i = 0; i < 4; ++i) {
    int row = m0 + ty * 4 + i;
    float4 o0 = {acc[i][0], acc[i][1], acc[i][2], acc[i][3]};
    float4 o1 = {acc[i][4], acc[i][5], acc[i][6], acc[i][7]};
    *(float4*)&C[(size_t)row * FF_ + c0 + tx * 8] = o0;
    *(float4*)&C[(size_t)row * FF_ + c0 + tx * 8 + 4] = o1;
  }
}

// =====================================================================
// K2: prefix sums over L for the two head projections
// =====================================================================
__global__ __launch_bounds__(256) void k2_prefix(float* __restrict__ ws) {
  int idx = blockIdx.x * 256 + threadIdx.x;       // 0..8191
  int mat = idx >> 12;
  int b = (idx >> 9) & 7;
  int f = idx & 511;
  const float* src = ws + (mat == 0 ? OFF_HH_ARG : OFF_HH_SRL) + (size_t)(b * L_) * D_ + f;
  float* dst = ws + (mat == 0 ? OFF_PH_ARG : OFF_PH_SRL) + (size_t)(b * (L_ + 1)) * D_ + f;
  float run = 0.f;
  dst[0] = 0.f;
  for (int l = 0; l < L_; ++l) {
    run += src[(size_t)l * D_];
    dst[(size_t)(l + 1) * D_] = run;
  }
}

// =====================================================================
// K3a: predicate FFN + p_srl  (32 blocks, one per (b,g))
// =====================================================================
__global__ __launch_bounds__(256) void k3a_pred(const float* __restrict__ hidden,
                                                const int* __restrict__ goldp,
                                                const float* __restrict__ pw0, const float* __restrict__ pb0,
                                                const float* __restrict__ pw1, const float* __restrict__ pb1,
                                                const float* __restrict__ pwp, const float* __restrict__ pbp,
                                                const float* __restrict__ srl_w0,
                                                float* __restrict__ ws) {
  __shared__ float emb[512], h0[512], h1[512], red[256];
  const int p = blockIdx.x, tid = threadIdx.x;
  const int b = p >> 2;
  const int pi = goldp[p];
  const float* hrow = hidden + (size_t)(b * L_ + pi) * D_;
  emb[tid] = hrow[tid];
  emb[tid + 256] = hrow[tid + 256];
  __syncthreads();
#pragma unroll
  for (int h = 0; h < 2; ++h) {
    int f = tid + h * 256;
    float a = pb0[f];
    for (int d = 0; d < D_; ++d) a += emb[d] * pw0[(size_t)d * FF_ + f];
    h0[f] = fmaxf(a, 0.f);
  }
  __syncthreads();
#pragma unroll
  for (int h = 0; h < 2; ++h) {
    int f = tid + h * 256;
    float a = pb1[f];
    for (int d = 0; d < FF_; ++d) a += h0[d] * pw1[(size_t)d * FF_ + f];
    h1[f] = fmaxf(a, 0.f);
  }
  __syncthreads();
  red[tid] = h1[tid] * pwp[tid] + h1[tid + 256] * pwp[tid + 256];
  __syncthreads();
  for (int s = 128; s > 0; s >>= 1) {
    if (tid < s) red[tid] += red[tid + s];
    __syncthreads();
  }
  if (tid == 0) ws[OFF_PSCORE + p] = red[0] + pbp[0];
#pragma unroll
  for (int h = 0; h < 2; ++h) {
    int f = tid + h * 256;
    float a = 0.f;
    for (int d = 0; d < D_; ++d) a += emb[d] * srl_w0[(size_t)(SPAN_ + d) * FF_ + f];
    ws[OFF_P_SRL + (size_t)p * FF_ + f] = a;
  }
}

// =====================================================================
// K3b: pred_scaled -> pred1 (+ trailing 1), and the two width tables
// grid = 32*7 + 2
// =====================================================================
__global__ __launch_bounds__(256) void k3b_scale(const float* __restrict__ hidden,
                                                 const int* __restrict__ goldp,
                                                 const float* __restrict__ scale_w,
                                                 const float* __restrict__ scale_b,
                                                 const float* __restrict__ wtab,
                                                 const float* __restrict__ arg_w0,
                                                 const float* __restrict__ srl_w0,
                                                 float* __restrict__ ws) {
  const int blk = blockIdx.x, tid = threadIdx.x;
  if (blk >= NP_ * 7) {
    int mat = blk - NP_ * 7;
    const float* W = (mat == 0 ? arg_w0 : srl_w0) + (size_t)(2 * D_) * FF_;
    float* dst = ws + (mat == 0 ? OFF_WD_ARG : OFF_WD_SRL);
    for (int idx = tid; idx < MAW_ * FF_; idx += 256) {
      int w = idx >> 9, f = idx & 511;
      float a = 0.f;
#pragma unroll
      for (int k = 0; k < SWF_; ++k) a += wtab[w * SWF_ + k] * W[(size_t)k * FF_ + f];
      dst[idx] = a;
    }
    return;
  }
  const int p = blk / 7, chunk = blk % 7;
  __shared__ float emb[512];
  const int b = p >> 2;
  const int pi = goldp[p];
  const float* hrow = hidden + (size_t)(b * L_ + pi) * D_;
  emb[tid] = hrow[tid];
  emb[tid + 256] = hrow[tid + 256];
  __syncthreads();
  const int i = chunk * 256 + tid;
  if (i < SPAN_) {
    float a = scale_b[i];
    for (int d = 0; d < D_; ++d) a += emb[d] * scale_w[(size_t)d * SPAN_ + i];
    ws[OFF_PRED1 + (size_t)p * S1_ + i] = fmaxf(a, 0.f);
  } else if (i == SPAN_) {
    ws[OFF_PRED1 + (size_t)p * S1_ + i] = 1.f;
  }
}

// =====================================================================
// K4: t[p][r*1557+i] = sum_j pred1[p][j] * bw[(r*1557+i)*1557 + j]
// GEMM M=29583 N=32 K=1557; tile 64x32, KC=32. Streams 184 MB of bw once.
// =====================================================================
__global__ __launch_bounds__(256) void k4_t(const float* __restrict__ bw,
                                            float* __restrict__ ws) {
  __shared__ float As[32][65];
  __shared__ float Bs[32][36];
  const float* pred1 = ws + OFF_PRED1;
  float* t = ws + OFF_T;
  const int tid = threadIdx.x;
  const int m0 = blockIdx.x * 64;
  const int tx = tid & 7, ty = tid >> 3;
  float acc[2][4] = {{0.f, 0.f, 0.f, 0.f}, {0.f, 0.f, 0.f, 0.f}};
  const int mlA = tid >> 2, kqA = (tid & 3) * 8;
  const int pB = tid & 31, kqB = (tid >> 5) * 4;

  for (int kc = 0; kc < 49; ++kc) {
    const int j0 = kc * 32;
    {
      const int m = m0 + mlA;
      const bool mok = m < TM_;
      const float* arow = bw + (size_t)m * S1_ + j0 + kqA;
#pragma unroll
      for (int q = 0; q < 8; ++q) {
        int jj = j0 + kqA + q;
        As[kqA + q][mlA] = (mok && jj < S1_) ? arow[q] : 0.f;
      }
    }
    {
#pragma unroll
      for (int q = 0; q < 4; ++q) {
        int jj = j0 + kqB + q;
        Bs[kqB + q][pB] = (jj < S1_) ? pred1[(size_t)pB * S1_ + jj] : 0.f;
      }
    }
    __syncthreads();
#pragma unroll
    for (int kk = 0; kk < 32; ++kk) {
      float a0 = As[kk][ty * 2], a1 = As[kk][ty * 2 + 1];
      float4 bq = *(const float4*)&Bs[kk][tx * 4];
      acc[0][0] += a0 * bq.x; acc[0][1] += a0 * bq.y;
      acc[0][2] += a0 * bq.z; acc[0][3] += a0 * bq.w;
      acc[1][0] += a1 * bq.x; acc[1][1] += a1 * bq.y;
      acc[1][2] += a1 * bq.z; acc[1][3] += a1 * bq.w;
    }
    __syncthreads();
  }
#pragma unroll
  for (int i2 = 0; i2 < 2; ++i2) {
    int m = m0 + ty * 2 + i2;
    if (m < TM_) {
#pragma unroll
      for (int q = 0; q < 4; ++q) t[(size_t)(tx * 4 + q) * TM_ + m] = acc[i2][q];
    }
  }
}

// =====================================================================
// K5: biaffine gather tables: Ms/Me/Mhp/Mw/tconst per (p,r). 608 blocks.
// =====================================================================
__global__ __launch_bounds__(256) void k5_biaff(const float* __restrict__ hidden,
                                                const float* __restrict__ wtab,
                                                float* __restrict__ ws) {
  __shared__ float trow[S1_];
  __shared__ float mh[128];
  const int pr = blockIdx.x;
  const int p = pr / R_;
  const int b = p >> 2;
  const float* t = ws + OFF_T + (size_t)p * TM_ + (size_t)(pr % R_) * S1_;
  const int tid = threadIdx.x;
  for (int idx = tid; idx < S1_; idx += 256) trow[idx] = t[idx];
  __syncthreads();
  const int wv = tid >> 6, lane = tid & 63;
  const float* hb = hidden + (size_t)b * L_ * D_;
#pragma unroll
  for (int seg = 0; seg < 3; ++seg) {
    const int off = (seg == 0) ? 0 : (seg == 1) ? 512 : 1044;
    for (int l = wv * 32; l < wv * 32 + 32; ++l) {
      float part = 0.f;
#pragma unroll
      for (int q = 0; q < 8; ++q) {
        int d = q * 64 + lane;
        part += hb[(size_t)l * D_ + d] * trow[off + d];
      }
#pragma unroll
      for (int o = 32; o > 0; o >>= 1) part += __shfl_xor(part, o);
      if (lane == 0) {
        if (seg == 0) ws[OFF_MS + (size_t)pr * 128 + l] = part;
        else if (seg == 1) ws[OFF_ME + (size_t)pr * 128 + l] = part;
        else mh[l] = part;
      }
    }
  }
  __syncthreads();
  if (tid == 0) {
    float run = 0.f;
    float* Mhp = ws + OFF_MHP + (size_t)pr * 129;
    Mhp[0] = 0.f;
    for (int l = 0; l < 128; ++l) { run += mh[l]; Mhp[l + 1] = run; }
    ws[OFF_TC + pr] = trow[1556];
  }
  if (tid < MAW_) {
    float a = 0.f;
#pragma unroll
    for (int k = 0; k < SWF_; ++k) a += wtab[tid * SWF_ + k] * trow[1024 + k];
    ws[OFF_MW + (size_t)pr * 8 + tid] = a;
  }
}

// =====================================================================
// K6: assemble span-level layer-0 activations (h_arg, a_srl) via gathers
// + init arg_scores (bias) and d_out (srl_bp). 8192 blocks.
// =====================================================================
__global__ __launch_bounds__(256) void k6_span(const int* __restrict__ slen,
                                               const float* __restrict__ arg_b0,
                                               const float* __restrict__ arg_bp,
                                               const float* __restrict__ srl_bp,
                                               float* __restrict__ ws,
                                               float* __restrict__ out) {
  const int sp = blockIdx.x, tid = threadIdx.x;
  const int b = sp >> 10, s = sp & 1023;
  const int w = s >> 7, l = s & 127;
  const bool valid = (l + w) < slen[b];
  const int st = valid ? l : 0;
  const int en = valid ? l + w : 0;
  const int wd = en - st;

  const float* HsA = ws + OFF_HS_ARG + (size_t)(b * 128 + st) * 512;
  const float* HeA = ws + OFF_HE_ARG + (size_t)(b * 128 + en) * 512;
  const float* PA1 = ws + OFF_PH_ARG + (size_t)(b * 129 + en + 1) * 512;
  const float* PA0 = ws + OFF_PH_ARG + (size_t)(b * 129 + st) * 512;
  const float* WdA = ws + OFF_WD_ARG + (size_t)wd * 512;
  const float* HsS = ws + OFF_HS_SRL + (size_t)(b * 128 + st) * 512;
  const float* HeS = ws + OFF_HE_SRL + (size_t)(b * 128 + en) * 512;
  const float* PS1 = ws + OFF_PH_SRL + (size_t)(b * 129 + en + 1) * 512;
  const float* PS0 = ws + OFF_PH_SRL + (size_t)(b * 129 + st) * 512;
  const float* WdS = ws + OFF_WD_SRL + (size_t)wd * 512;
  float* ha = ws + OFF_HARG + (size_t)sp * 512;
  float* as = ws + OFF_ASRL + (size_t)sp * 512;

#pragma unroll
  for (int h = 0; h < 2; ++h) {
    int f = tid + h * 256;
    float va = HsA[f] + HeA[f] + WdA[f] + (PA1[f] - PA0[f]) * 0.125f + arg_b0[f];
    ha[f] = fmaxf(va, 0.f);
    as[f] = HsS[f] + HeS[f] + WdS[f] + (PS1[f] - PS0[f]) * 0.125f;
  }
  if (tid == 0) ws[OFF_ARGS + sp] = arg_bp[0];
  if (tid < G_ * R_) {
    int g = tid / R_, r = tid % R_;
    out[((size_t)sp * G_ + g) * R_ + r] = srl_bp[r];
  }
}

// =====================================================================
// K7: arg FFN layer1 + wp projection. GEMM M=8192 N=512 K=512.
// tile 128x128, KC=16, epilogue: relu + dot(arg_wp) -> atomicAdd scores
// =====================================================================
__global__ __launch_bounds__(256) void k7_arg(const float* __restrict__ w1,
                                              const float* __restrict__ b1,
                                              const float* __restrict__ wp,
                                              float* __restrict__ ws) {
  __shared__ float As[16][136];
  __shared__ float Bs[16][132];
  __shared__ float wps[128];
  const float* A = ws + OFF_HARG;
  float* scores = ws + OFF_ARGS;
  const int tid = threadIdx.x;
  const int m0 = blockIdx.x * 128, n0 = blockIdx.y * 128;
  if (tid < 128) wps[tid] = wp[n0 + tid];
  const int tx = tid & 15, ty = tid >> 4;
  float acc[8][8];
#pragma unroll
  for (int i = 0; i < 8; ++i)
#pragma unroll
    for (int jj = 0; jj < 8; ++jj) acc[i][jj] = 0.f;
  const int mlA = tid >> 1, khA = (tid & 1) * 8;
  const int n4B = (tid & 31) * 4, krB = tid >> 5;

  for (int kc = 0; kc < 32; ++kc) {
    {
      const float* ar = &A[(size_t)(m0 + mlA) * 512 + kc * 16 + khA];
      float4 x0 = *(const float4*)ar, x1 = *(const float4*)(ar + 4);
      As[khA + 0][mlA] = x0.x; As[khA + 1][mlA] = x0.y;
      As[khA + 2][mlA] = x0.z; As[khA + 3][mlA] = x0.w;
      As[khA + 4][mlA] = x1.x; As[khA + 5][mlA] = x1.y;
      As[khA + 6][mlA] = x1.z; As[khA + 7][mlA] = x1.w;
    }
#pragma unroll
    for (int it = 0; it < 2; ++it) {
      int k = krB + it * 8;
      *(float4*)&Bs[k][n4B] = *(const float4*)&w1[(size_t)(kc * 16 + k) * 512 + n0 + n4B];
    }
    __syncthreads();
#pragma unroll
    for (int kk = 0; kk < 16; ++kk) {
      float4 a0 = *(const float4*)&As[kk][ty * 8];
      float4 a1 = *(const float4*)&As[kk][ty * 8 + 4];
      float4 v0 = *(const float4*)&Bs[kk][tx * 8];
      float4 v1 = *(const float4*)&Bs[kk][tx * 8 + 4];
      float ar[8] = {a0.x, a0.y, a0.z, a0.w, a1.x, a1.y, a1.z, a1.w};
      float br[8] = {v0.x, v0.y, v0.z, v0.w, v1.x, v1.y, v1.z, v1.w};
#pragma unroll
      for (int i = 0; i < 8; ++i)
#pragma unroll
        for (int jj = 0; jj < 8; ++jj) acc[i][jj] += ar[i] * br[jj];
    }
    __syncthreads();
  }
  float bj[8];
#pragma unroll
  for (int jj = 0; jj < 8; ++jj) bj[jj] = b1[n0 + tx * 8 + jj];
#pragma unroll
  for (int i = 0; i < 8; ++i) {
    float part = 0.f;
#pragma unroll
    for (int jj = 0; jj < 8; ++jj)
      part += fmaxf(acc[i][jj] + bj[jj], 0.f) * wps[tx * 8 + jj];
#pragma unroll
    for (int o = 1; o < 16; o <<= 1) part += __shfl_xor(part, o);
    if (tx == 0) atomicAdd(&scores[m0 + ty * 8 + i], part);
  }
}

// =====================================================================
// K8: pairwise SRL GEMM (the big one). M=32768 N=512 K=512.
// A constructed on the fly: relu(a_srl[span] + p_srl[pred] + srl_b0).
// Epilogue: relu(+b1), multiply by srl_wp (512x19), shuffle-reduce over
// the 16 tx lanes, atomicAdd into d_out (pre-initialized with srl_bp).
// =====================================================================
__global__ __launch_bounds__(256) void k8_srl(const float* __restrict__ w1,
                                              const float* __restrict__ b1,
                                              const float* __restrict__ wp,
                                              const float* __restrict__ b0,
                                              float* __restrict__ ws,
                                              float* __restrict__ out) {
  __shared__ float As[16][136];
  __shared__ float Bs[16][132];
  __shared__ float wps[128 * 19];
  const float* a_srl = ws + OFF_ASRL;
  const float* p_srl = ws + OFF_P_SRL;
  const int tid = threadIdx.x;
  const int m0 = blockIdx.x * 128, n0 = blockIdx.y * 128;
  for (int idx = tid; idx < 128 * 19; idx += 256) wps[idx] = wp[(size_t)n0 * 19 + idx];
  const int tx = tid & 15, ty = tid >> 4;
  float acc[8][8];
#pragma unroll
  for (int i = 0; i < 8; ++i)
#pragma unroll
    for (int jj = 0; jj < 8; ++jj) acc[i][jj] = 0.f;
  const int mlA = tid >> 1, khA = (tid & 1) * 8;
  const int m = m0 + mlA;
  const int sprow = m >> 2;
  const int prow = ((m >> 12) << 2) | (m & 3);
  const float* arow = a_srl + (size_t)sprow * 512;
  const float* prp = p_srl + (size_t)prow * 512;
  const int n4B = (tid & 31) * 4, krB = tid >> 5;

  for (int kc = 0; kc < 32; ++kc) {
    {
      const int kb = kc * 16 + khA;
      float4 x0 = *(const float4*)&arow[kb], x1 = *(const float4*)&arow[kb + 4];
      float4 y0 = *(const float4*)&prp[kb], y1 = *(const float4*)&prp[kb + 4];
      float4 z0 = *(const float4*)&b0[kb], z1 = *(const float4*)&b0[kb + 4];
      As[khA + 0][mlA] = fmaxf(x0.x + y0.x + z0.x, 0.f);
      As[khA + 1][mlA] = fmaxf(x0.y + y0.y + z0.y, 0.f);
      As[khA + 2][mlA] = fmaxf(x0.z + y0.z + z0.z, 0.f);
      As[khA + 3][mlA] = fmaxf(x0.w + y0.w + z0.w, 0.f);
      As[khA + 4][mlA] = fmaxf(x1.x + y1.x + z1.x, 0.f);
      As[khA + 5][mlA] = fmaxf(x1.y + y1.y + z1.y, 0.f);
      As[khA + 6][mlA] = fmaxf(x1.z + y1.z + z1.z, 0.f);
      As[khA + 7][mlA] = fmaxf(x1.w + y1.w + z1.w, 0.f);
    }
#pragma unroll
    for (int it = 0; it < 2; ++it) {
      int k = krB + it * 8;
      *(float4*)&Bs[k][n4B] = *(const float4*)&w1[(size_t)(kc * 16 + k) * 512 + n0 + n4B];
    }
    __syncthreads();
#pragma unroll
    for (int kk = 0; kk < 16; ++kk) {
      float4 a0 = *(const float4*)&As[kk][ty * 8];
      float4 a1 = *(const float4*)&As[kk][ty * 8 + 4];
      float4 v0 = *(const float4*)&Bs[kk][tx * 8];
      float4 v1 = *(const float4*)&Bs[kk][tx * 8 + 4];
      float ar[8] = {a0.x, a0.y, a0.z, a0.w, a1.x, a1.y, a1.z, a1.w};
      float br[8] = {v0.x, v0.y, v0.z, v0.w, v1.x, v1.y, v1.z, v1.w};
#pragma unroll
      for (int i = 0; i < 8; ++i)
#pragma unroll
        for (int jj = 0; jj < 8; ++jj) acc[i][jj] += ar[i] * br[jj];
    }
    __syncthreads();
  }
  float bj[8];
#pragma unroll
  for (int jj = 0; jj < 8; ++jj) bj[jj] = b1[n0 + tx * 8 + jj];
#pragma unroll
  for (int i = 0; i < 8; ++i) {
    float pr_[19];
#pragma unroll
    for (int r = 0; r < 19; ++r) pr_[r] = 0.f;
#pragma unroll
    for (int jj = 0; jj < 8; ++jj) {
      float v = fmaxf(acc[i][jj] + bj[jj], 0.f);
      const float* wrow = &wps[(tx * 8 + jj) * 19];
#pragma unroll
      for (int r = 0; r < 19; ++r) pr_[r] += v * wrow[r];
    }
#pragma unroll
    for (int o = 1; o < 16; o <<= 1) {
#pragma unroll
      for (int r = 0; r < 19; ++r) pr_[r] += __shfl_xor(pr_[r], o);
    }
    if (tx == 0) {
      size_t row = (size_t)(m0 + ty * 8 + i);
#pragma unroll
      for (int r = 0; r < 19; ++r) atomicAdd(&out[row * 19 + r], pr_[r]);
    }
  }
}

// =====================================================================
// K9: finalize: add biaffine gathers + arg/pred scores, apply mask.
// =====================================================================
__global__ __launch_bounds__(128) void k9_fin(const int* __restrict__ slen,
                                              float* __restrict__ out,
                                              const float* __restrict__ ws) {
  const int sp = blockIdx.x, tid = threadIdx.x;
  if (tid >= G_ * R_) return;
  const int b = sp >> 10, s = sp & 1023;
  const int w = s >> 7, l = s & 127;
  const bool valid = (l + w) < slen[b];
  const int st = valid ? l : 0;
  const int en = valid ? l + w : 0;
  const int wd = en - st;
  const int g = tid / R_, r = tid % R_;
  const int p = b * G_ + g;
  const int pr = p * R_ + r;
  const size_t o = ((size_t)sp * G_ + g) * R_ + r;
  float val = out[o]
            + ws[OFF_MS + (size_t)pr * 128 + st]
            + ws[OFF_ME + (size_t)pr * 128 + en]
            + ws[OFF_MW + (size_t)pr * 8 + wd]
            + (ws[OFF_MHP + (size_t)pr * 129 + en + 1] - ws[OFF_MHP + (size_t)pr * 129 + st]) * 0.125f
            + ws[OFF_TC + pr]
            + ws[OFF_ARGS + sp]
            + ws[OFF_PSCORE + p];
  out[o] = valid ? val : 0.f;
}

// =====================================================================
extern "C" void kernel_launch(void* const* d_in, const int* in_sizes, int n_in,
                              void* d_out, int out_size, void* d_ws, size_t ws_size,
                              hipStream_t stream) {
  const float* hidden  = (const float*)d_in[0];
  const int*   slen    = (const int*)d_in[1];
  const int*   goldp   = (const int*)d_in[2];
  const float* wtab    = (const float*)d_in[3];
  const float* arg_w0  = (const float*)d_in[4];
  const float* arg_b0  = (const float*)d_in[5];
  const float* arg_w1  = (const float*)d_in[6];
  const float* arg_b1  = (const float*)d_in[7];
  const float* arg_wp  = (const float*)d_in[8];
  const float* arg_bp  = (const float*)d_in[9];
  const float* pred_w0 = (const float*)d_in[10];
  const float* pred_b0 = (const float*)d_in[11];
  const float* pred_w1 = (const float*)d_in[12];
  const float* pred_b1 = (const float*)d_in[13];
  const float* pred_wp = (const float*)d_in[14];
  const float* pred_bp = (const float*)d_in[15];
  const float* srl_w0  = (const float*)d_in[16];
  const float* srl_b0  = (const float*)d_in[17];
  const float* srl_w1  = (const float*)d_in[18];
  const float* srl_b1  = (const float*)d_in[19];
  const float* srl_wp  = (const float*)d_in[20];
  const float* srl_bp  = (const float*)d_in[21];
  const float* scale_w = (const float*)d_in[22];
  const float* scale_b = (const float*)d_in[23];
  const float* bw      = (const float*)d_in[24];
  float* out = (float*)d_out;
  float* ws  = (float*)d_ws;

  k1_proj<<<dim3(16, 24), 256, 0, stream>>>(hidden, arg_w0, srl_w0, ws);
  k2_prefix<<<32, 256, 0, stream>>>(ws);
  k3a_pred<<<32, 256, 0, stream>>>(hidden, goldp, pred_w0, pred_b0, pred_w1, pred_b1,
                                   pred_wp, pred_bp, srl_w0, ws);
  k3b_scale<<<NP_ * 7 + 2, 256, 0, stream>>>(hidden, goldp, scale_w, scale_b, wtab,
                                             arg_w0, srl_w0, ws);
  k4_t<<<(TM_ + 63) / 64, 256, 0, stream>>>(bw, ws);
  k5_biaff<<<NP_ * R_, 256, 0, stream>>>(hidden, wtab, ws);
  k6_span<<<NS_, 256, 0, stream>>>(slen, arg_b0, arg_bp, srl_bp, ws, out);
  k7_arg<<<dim3(NS_ / 128, 4), 256, 0, stream>>>(arg_w1, arg_b1, arg_wp, ws);
  k8_srl<<<dim3(M8_ / 128, 4), 256, 0, stream>>>(srl_w1, srl_b1, srl_wp, srl_b0, ws, out);
  k9_fin<<<NS_, 128, 0, stream>>>(slen, out, ws);
}

// Round 3
// 1142.269 us; speedup vs baseline: 1.0089x; 1.0089x over previous
//
#include <hip/hip_runtime.h>

// ---------------- problem constants ----------------
constexpr int B_   = 8;
constexpr int L_   = 128;
constexpr int D_   = 512;
constexpr int MAW_ = 8;
constexpr int SWF_ = 20;
constexpr int FF_  = 512;
constexpr int R_   = 19;
constexpr int G_   = 4;
constexpr int SPAN_ = 3 * D_ + SWF_;   // 1556
constexpr int S1_   = SPAN_ + 1;       // 1557
constexpr int S_    = L_ * MAW_;       // 1024 spans / batch
constexpr int NS_   = B_ * S_;         // 8192 spans total
constexpr int NP_   = B_ * G_;         // 32 predicates
constexpr int TM_   = R_ * S1_;        // 29583 rows of biaffine_w
constexpr int M8_   = NS_ * G_;        // 32768 pairwise rows

// ---------------- workspace layout (float offsets) ----------------
constexpr size_t OFF_HS_ARG = 0;               // 6 x 1024x512 projections
constexpr size_t OFF_HE_ARG = 524288;
constexpr size_t OFF_HH_ARG = 1048576;
constexpr size_t OFF_HS_SRL = 1572864;
constexpr size_t OFF_HE_SRL = 2097152;
constexpr size_t OFF_HH_SRL = 2621440;
constexpr size_t OFF_PH_ARG = 3145728;         // 8 x 129 x 512 prefix
constexpr size_t OFF_PH_SRL = 3674112;
constexpr size_t OFF_P_SRL  = 4202496;         // 32 x 512
constexpr size_t OFF_PSCORE = 4218880;         // 32
constexpr size_t OFF_PRED1  = 4218912;         // 32 x 1557
constexpr size_t OFF_WD_ARG = 4268736;         // 8 x 512
constexpr size_t OFF_WD_SRL = 4272832;         // 8 x 512
constexpr size_t OFF_T      = 4276928;         // 32 x 29583  [p][r*1557+i]
constexpr size_t OFF_MS     = 5223584;         // 608 x 128
constexpr size_t OFF_ME     = 5301408;         // 608 x 128
constexpr size_t OFF_MHP    = 5379232;         // 608 x 129
constexpr size_t OFF_MW     = 5457664;         // 608 x 8
constexpr size_t OFF_TC     = 5462528;         // 608
constexpr size_t OFF_HARG   = 5463136;         // 8192 x 512 BF16 (lower half of old fp32 region)
constexpr size_t OFF_W1T_ARG = 7560288;        // 512x512 bf16 (as 131072 floats), inside old HARG region
constexpr size_t OFF_W1T_SRL = 7691360;        // 512x512 bf16
constexpr size_t OFF_ASRL   = 9657440;         // 8192 x 512 fp32
constexpr size_t OFF_ARGS   = 13851744;        // 8192
// total = 13,859,936 floats = 55.4 MB (unchanged)

typedef short bf16x8 __attribute__((ext_vector_type(8)));
typedef float f32x4  __attribute__((ext_vector_type(4)));

__device__ __forceinline__ unsigned short f2bf(float x) {
  unsigned u = __float_as_uint(x);
  unsigned r = (u + 0x7FFFu + ((u >> 16) & 1u)) >> 16;   // RNE
  return (unsigned short)r;
}

// =====================================================================
// K1: six per-token projections  Hx = hidden(1024x512) @ W(512x512)
// =====================================================================
__global__ __launch_bounds__(256) void k1_proj(const float* __restrict__ hidden,
                                               const float* __restrict__ arg_w0,
                                               const float* __restrict__ srl_w0,
                                               float* __restrict__ ws) {
  __shared__ float As[16][68];
  __shared__ float Bs[16][132];
  const int tid = threadIdx.x;
  const int m0 = blockIdx.x * 64;
  const int by = blockIdx.y;
  const int j = by >> 2;               // which projection 0..5
  const int c0 = (by & 3) * 128;       // col offset within projection
  const int rowoffs[3] = {0, 512, 1044};
  const float* W = (j < 3) ? (arg_w0 + (size_t)rowoffs[j] * FF_)
                           : (srl_w0 + (size_t)rowoffs[j - 3] * FF_);
  float* C = ws + (size_t)j * 524288;

  const int tx = tid & 15, ty = tid >> 4;
  float acc[4][8];
#pragma unroll
  for (int i = 0; i < 4; ++i)
#pragma unroll
    for (int jj = 0; jj < 8; ++jj) acc[i][jj] = 0.f;

  const int mlA = tid >> 2, kqA = (tid & 3) * 4;
  const int n4B = (tid & 31) * 4, krB = tid >> 5;

  for (int kc = 0; kc < 32; ++kc) {
    float4 av = *(const float4*)&hidden[(size_t)(m0 + mlA) * D_ + kc * 16 + kqA];
    As[kqA + 0][mlA] = av.x; As[kqA + 1][mlA] = av.y;
    As[kqA + 2][mlA] = av.z; As[kqA + 3][mlA] = av.w;
#pragma unroll
    for (int it = 0; it < 2; ++it) {
      int k = krB + it * 8;
      *(float4*)&Bs[k][n4B] = *(const float4*)&W[(size_t)(kc * 16 + k) * FF_ + c0 + n4B];
    }
    __syncthreads();
#pragma unroll
    for (int kk = 0; kk < 16; ++kk) {
      float4 a  = *(const float4*)&As[kk][ty * 4];
      float4 b0 = *(const float4*)&Bs[kk][tx * 8];
      float4 b1 = *(const float4*)&Bs[kk][tx * 8 + 4];
      float ar[4] = {a.x, a.y, a.z, a.w};
      float br[8] = {b0.x, b0.y, b0.z, b0.w, b1.x, b1.y, b1.z, b1.w};
#pragma unroll
      for (int i = 0; i < 4; ++i)
#pragma unroll
        for (int jj = 0; jj < 8; ++jj) acc[i][jj] += ar[i] * br[jj];
    }
    __syncthreads();
  }
#pragma unroll
  for (int i = 0; i < 4; ++i) {
    int row = m0 + ty * 4 + i;
    float4 o0 = {acc[i][0], acc[i][1], acc[i][2], acc[i][3]};
    float4 o1 = {acc[i][4], acc[i][5], acc[i][6], acc[i][7]};
    *(float4*)&C[(size_t)row * FF_ + c0 + tx * 8] = o0;
    *(float4*)&C[(size_t)row * FF_ + c0 + tx * 8 + 4] = o1;
  }
}

// =====================================================================
// KW: transpose + bf16-convert arg_w1 / srl_w1 -> w1T[n][k]
// =====================================================================
__global__ __launch_bounds__(256) void kw_cvt(const float* __restrict__ arg_w1,
                                              const float* __restrict__ srl_w1,
                                              float* __restrict__ ws) {
  __shared__ float tile[64][65];
  const int mat = blockIdx.z;
  const float* W = mat ? srl_w1 : arg_w1;
  unsigned short* T = (unsigned short*)(ws + (mat ? OFF_W1T_SRL : OFF_W1T_ARG));
  const int k0 = blockIdx.x * 64, n0 = blockIdx.y * 64;
  const int t = threadIdx.x;
  const int kk = t >> 4, nn = (t & 15) * 4;
#pragma unroll
  for (int it = 0; it < 4; ++it) {
    float4 v = *(const float4*)&W[(size_t)(k0 + kk + it * 16) * 512 + n0 + nn];
    tile[kk + it * 16][nn + 0] = v.x; tile[kk + it * 16][nn + 1] = v.y;
    tile[kk + it * 16][nn + 2] = v.z; tile[kk + it * 16][nn + 3] = v.w;
  }
  __syncthreads();
  const int n = t >> 2, kc = (t & 3) * 16;
  unsigned o[8];
#pragma unroll
  for (int j2 = 0; j2 < 8; ++j2) {
    unsigned lo = f2bf(tile[kc + 2 * j2][n]);
    unsigned hi = f2bf(tile[kc + 2 * j2 + 1][n]);
    o[j2] = lo | (hi << 16);
  }
  uint4 u0 = {o[0], o[1], o[2], o[3]}, u1 = {o[4], o[5], o[6], o[7]};
  unsigned short* dst = &T[(size_t)(n0 + n) * 512 + k0 + kc];
  *(uint4*)dst = u0;
  *(uint4*)(dst + 8) = u1;
}

// =====================================================================
// K2: prefix sums over L for the two head projections
// =====================================================================
__global__ __launch_bounds__(256) void k2_prefix(float* __restrict__ ws) {
  int idx = blockIdx.x * 256 + threadIdx.x;       // 0..8191
  int mat = idx >> 12;
  int b = (idx >> 9) & 7;
  int f = idx & 511;
  const float* src = ws + (mat == 0 ? OFF_HH_ARG : OFF_HH_SRL) + (size_t)(b * L_) * D_ + f;
  float* dst = ws + (mat == 0 ? OFF_PH_ARG : OFF_PH_SRL) + (size_t)(b * (L_ + 1)) * D_ + f;
  float run = 0.f;
  dst[0] = 0.f;
  for (int l = 0; l < L_; ++l) {
    run += src[(size_t)l * D_];
    dst[(size_t)(l + 1) * D_] = run;
  }
}

// =====================================================================
// K3a: predicate FFN + p_srl  (32 blocks, one per (b,g))
// =====================================================================
__global__ __launch_bounds__(256) void k3a_pred(const float* __restrict__ hidden,
                                                const int* __restrict__ goldp,
                                                const float* __restrict__ pw0, const float* __restrict__ pb0,
                                                const float* __restrict__ pw1, const float* __restrict__ pb1,
                                                const float* __restrict__ pwp, const float* __restrict__ pbp,
                                                const float* __restrict__ srl_w0,
                                                float* __restrict__ ws) {
  __shared__ float emb[512], h0[512], h1[512], red[256];
  const int p = blockIdx.x, tid = threadIdx.x;
  const int b = p >> 2;
  const int pi = goldp[p];
  const float* hrow = hidden + (size_t)(b * L_ + pi) * D_;
  emb[tid] = hrow[tid];
  emb[tid + 256] = hrow[tid + 256];
  __syncthreads();
#pragma unroll
  for (int h = 0; h < 2; ++h) {
    int f = tid + h * 256;
    float a = pb0[f];
    for (int d = 0; d < D_; ++d) a += emb[d] * pw0[(size_t)d * FF_ + f];
    h0[f] = fmaxf(a, 0.f);
  }
  __syncthreads();
#pragma unroll
  for (int h = 0; h < 2; ++h) {
    int f = tid + h * 256;
    float a = pb1[f];
    for (int d = 0; d < FF_; ++d) a += h0[d] * pw1[(size_t)d * FF_ + f];
    h1[f] = fmaxf(a, 0.f);
  }
  __syncthreads();
  red[tid] = h1[tid] * pwp[tid] + h1[tid + 256] * pwp[tid + 256];
  __syncthreads();
  for (int s = 128; s > 0; s >>= 1) {
    if (tid < s) red[tid] += red[tid + s];
    __syncthreads();
  }
  if (tid == 0) ws[OFF_PSCORE + p] = red[0] + pbp[0];
#pragma unroll
  for (int h = 0; h < 2; ++h) {
    int f = tid + h * 256;
    float a = 0.f;
    for (int d = 0; d < D_; ++d) a += emb[d] * srl_w0[(size_t)(SPAN_ + d) * FF_ + f];
    ws[OFF_P_SRL + (size_t)p * FF_ + f] = a;
  }
}

// =====================================================================
// K3b: pred_scaled -> pred1 (+ trailing 1), and the two width tables
// =====================================================================
__global__ __launch_bounds__(256) void k3b_scale(const float* __restrict__ hidden,
                                                 const int* __restrict__ goldp,
                                                 const float* __restrict__ scale_w,
                                                 const float* __restrict__ scale_b,
                                                 const float* __restrict__ wtab,
                                                 const float* __restrict__ arg_w0,
                                                 const float* __restrict__ srl_w0,
                                                 float* __restrict__ ws) {
  const int blk = blockIdx.x, tid = threadIdx.x;
  if (blk >= NP_ * 7) {
    int mat = blk - NP_ * 7;
    const float* W = (mat == 0 ? arg_w0 : srl_w0) + (size_t)(2 * D_) * FF_;
    float* dst = ws + (mat == 0 ? OFF_WD_ARG : OFF_WD_SRL);
    for (int idx = tid; idx < MAW_ * FF_; idx += 256) {
      int w = idx >> 9, f = idx & 511;
      float a = 0.f;
#pragma unroll
      for (int k = 0; k < SWF_; ++k) a += wtab[w * SWF_ + k] * W[(size_t)k * FF_ + f];
      dst[idx] = a;
    }
    return;
  }
  const int p = blk / 7, chunk = blk % 7;
  __shared__ float emb[512];
  const int b = p >> 2;
  const int pi = goldp[p];
  const float* hrow = hidden + (size_t)(b * L_ + pi) * D_;
  emb[tid] = hrow[tid];
  emb[tid + 256] = hrow[tid + 256];
  __syncthreads();
  const int i = chunk * 256 + tid;
  if (i < SPAN_) {
    float a = scale_b[i];
    for (int d = 0; d < D_; ++d) a += emb[d] * scale_w[(size_t)d * SPAN_ + i];
    ws[OFF_PRED1 + (size_t)p * S1_ + i] = fmaxf(a, 0.f);
  } else if (i == SPAN_) {
    ws[OFF_PRED1 + (size_t)p * S1_ + i] = 1.f;
  }
}

// =====================================================================
// K4: t[p][r*1557+i] = sum_j pred1[p][j] * bw[(r*1557+i)*1557 + j]
// =====================================================================
__global__ __launch_bounds__(256) void k4_t(const float* __restrict__ bw,
                                            float* __restrict__ ws) {
  __shared__ float As[32][65];
  __shared__ float Bs[32][36];
  const float* pred1 = ws + OFF_PRED1;
  float* t = ws + OFF_T;
  const int tid = threadIdx.x;
  const int m0 = blockIdx.x * 64;
  const int tx = tid & 7, ty = tid >> 3;
  float acc[2][4] = {{0.f, 0.f, 0.f, 0.f}, {0.f, 0.f, 0.f, 0.f}};
  const int mlA = tid >> 2, kqA = (tid & 3) * 8;
  const int pB = tid & 31, kqB = (tid >> 5) * 4;

  for (int kc = 0; kc < 49; ++kc) {
    const int j0 = kc * 32;
    {
      const int m = m0 + mlA;
      const bool mok = m < TM_;
      const float* arow = bw + (size_t)m * S1_ + j0 + kqA;
#pragma unroll
      for (int q = 0; q < 8; ++q) {
        int jj = j0 + kqA + q;
        As[kqA + q][mlA] = (mok && jj < S1_) ? arow[q] : 0.f;
      }
    }
    {
#pragma unroll
      for (int q = 0; q < 4; ++q) {
        int jj = j0 + kqB + q;
        Bs[kqB + q][pB] = (jj < S1_) ? pred1[(size_t)pB * S1_ + jj] : 0.f;
      }
    }
    __syncthreads();
#pragma unroll
    for (int kk = 0; kk < 32; ++kk) {
      float a0 = As[kk][ty * 2], a1 = As[kk][ty * 2 + 1];
      float4 bq = *(const float4*)&Bs[kk][tx * 4];
      acc[0][0] += a0 * bq.x; acc[0][1] += a0 * bq.y;
      acc[0][2] += a0 * bq.z; acc[0][3] += a0 * bq.w;
      acc[1][0] += a1 * bq.x; acc[1][1] += a1 * bq.y;
      acc[1][2] += a1 * bq.z; acc[1][3] += a1 * bq.w;
    }
    __syncthreads();
  }
#pragma unroll
  for (int i2 = 0; i2 < 2; ++i2) {
    int m = m0 + ty * 2 + i2;
    if (m < TM_) {
#pragma unroll
      for (int q = 0; q < 4; ++q) t[(size_t)(tx * 4 + q) * TM_ + m] = acc[i2][q];
    }
  }
}

// =====================================================================
// K5: biaffine gather tables: Ms/Me/Mhp/Mw/tconst per (p,r). 608 blocks.
// =====================================================================
__global__ __launch_bounds__(256) void k5_biaff(const float* __restrict__ hidden,
                                                const float* __restrict__ wtab,
                                                float* __restrict__ ws) {
  __shared__ float trow[S1_];
  __shared__ float mh[128];
  const int pr = blockIdx.x;
  const int p = pr / R_;
  const int b = p >> 2;
  const float* t = ws + OFF_T + (size_t)p * TM_ + (size_t)(pr % R_) * S1_;
  const int tid = threadIdx.x;
  for (int idx = tid; idx < S1_; idx += 256) trow[idx] = t[idx];
  __syncthreads();
  const int wv = tid >> 6, lane = tid & 63;
  const float* hb = hidden + (size_t)b * L_ * D_;
#pragma unroll
  for (int seg = 0; seg < 3; ++seg) {
    const int off = (seg == 0) ? 0 : (seg == 1) ? 512 : 1044;
    for (int l = wv * 32; l < wv * 32 + 32; ++l) {
      float part = 0.f;
#pragma unroll
      for (int q = 0; q < 8; ++q) {
        int d = q * 64 + lane;
        part += hb[(size_t)l * D_ + d] * trow[off + d];
      }
#pragma unroll
      for (int o = 32; o > 0; o >>= 1) part += __shfl_xor(part, o);
      if (lane == 0) {
        if (seg == 0) ws[OFF_MS + (size_t)pr * 128 + l] = part;
        else if (seg == 1) ws[OFF_ME + (size_t)pr * 128 + l] = part;
        else mh[l] = part;
      }
    }
  }
  __syncthreads();
  if (tid == 0) {
    float run = 0.f;
    float* Mhp = ws + OFF_MHP + (size_t)pr * 129;
    Mhp[0] = 0.f;
    for (int l = 0; l < 128; ++l) { run += mh[l]; Mhp[l + 1] = run; }
    ws[OFF_TC + pr] = trow[1556];
  }
  if (tid < MAW_) {
    float a = 0.f;
#pragma unroll
    for (int k = 0; k < SWF_; ++k) a += wtab[tid * SWF_ + k] * trow[1024 + k];
    ws[OFF_MW + (size_t)pr * 8 + tid] = a;
  }
}

// =====================================================================
// K6: assemble span-level layer-0 activations. HARG now stored BF16.
// =====================================================================
__global__ __launch_bounds__(256) void k6_span(const int* __restrict__ slen,
                                               const float* __restrict__ arg_b0,
                                               const float* __restrict__ arg_bp,
                                               const float* __restrict__ srl_bp,
                                               float* __restrict__ ws,
                                               float* __restrict__ out) {
  const int sp = blockIdx.x, tid = threadIdx.x;
  const int b = sp >> 10, s = sp & 1023;
  const int w = s >> 7, l = s & 127;
  const bool valid = (l + w) < slen[b];
  const int st = valid ? l : 0;
  const int en = valid ? l + w : 0;
  const int wd = en - st;

  const float* HsA = ws + OFF_HS_ARG + (size_t)(b * 128 + st) * 512;
  const float* HeA = ws + OFF_HE_ARG + (size_t)(b * 128 + en) * 512;
  const float* PA1 = ws + OFF_PH_ARG + (size_t)(b * 129 + en + 1) * 512;
  const float* PA0 = ws + OFF_PH_ARG + (size_t)(b * 129 + st) * 512;
  const float* WdA = ws + OFF_WD_ARG + (size_t)wd * 512;
  const float* HsS = ws + OFF_HS_SRL + (size_t)(b * 128 + st) * 512;
  const float* HeS = ws + OFF_HE_SRL + (size_t)(b * 128 + en) * 512;
  const float* PS1 = ws + OFF_PH_SRL + (size_t)(b * 129 + en + 1) * 512;
  const float* PS0 = ws + OFF_PH_SRL + (size_t)(b * 129 + st) * 512;
  const float* WdS = ws + OFF_WD_SRL + (size_t)wd * 512;
  unsigned short* ha = (unsigned short*)(ws + OFF_HARG) + (size_t)sp * 512;
  float* as = ws + OFF_ASRL + (size_t)sp * 512;

#pragma unroll
  for (int h = 0; h < 2; ++h) {
    int f = tid + h * 256;
    float va = HsA[f] + HeA[f] + WdA[f] + (PA1[f] - PA0[f]) * 0.125f + arg_b0[f];
    ha[f] = f2bf(fmaxf(va, 0.f));
    as[f] = HsS[f] + HeS[f] + WdS[f] + (PS1[f] - PS0[f]) * 0.125f;
  }
  if (tid == 0) ws[OFF_ARGS + sp] = arg_bp[0];
  if (tid < G_ * R_) {
    int g = tid / R_, r = tid % R_;
    out[((size_t)sp * G_ + g) * R_ + r] = srl_bp[r];
  }
}

// =====================================================================
// K7: arg FFN layer1 via BF16 MFMA. M=8192 N=512 K=512, tile 128x128.
// Swapped-operand mfma: D = w1T-frag x h-frag => D rows = n, cols = m,
// so the wp-projection n-reduction is mostly lane-local.
// =====================================================================
__global__ __launch_bounds__(256) void k7_arg(const float* __restrict__ b1,
                                              const float* __restrict__ wp,
                                              float* __restrict__ ws) {
  __shared__ short As[128 * 40];   // pitch 40 bf16 = 80 B -> even bank spread
  __shared__ short Bs[128 * 40];
  __shared__ float wps[128];
  __shared__ float bs1[128];
  const unsigned short* Aall = (const unsigned short*)(ws + OFF_HARG);
  const unsigned short* Ball = (const unsigned short*)(ws + OFF_W1T_ARG);
  float* scores = ws + OFF_ARGS;
  const int tid = threadIdx.x;
  const int m0 = blockIdx.x * 128, n0 = blockIdx.y * 128;
  if (tid < 128) { wps[tid] = wp[n0 + tid]; bs1[tid] = b1[n0 + tid]; }
  const int lane = tid & 63, wv = tid >> 6;
  const int wr = wv >> 1, wc = wv & 1;
  const int col = lane & 15, kg = lane >> 4;
  const int sm = tid >> 1, sh = tid & 1;
  const int bn = tid >> 2, bc = tid & 3;
  f32x4 acc[4][4];
#pragma unroll
  for (int i = 0; i < 4; ++i)
#pragma unroll
    for (int j = 0; j < 4; ++j) {
      acc[i][j][0] = 0.f; acc[i][j][1] = 0.f; acc[i][j][2] = 0.f; acc[i][j][3] = 0.f;
    }

  for (int kc = 0; kc < 16; ++kc) {
    {
      const unsigned short* src = &Aall[(size_t)(m0 + sm) * 512 + kc * 32 + sh * 16];
      *(uint4*)&As[sm * 40 + sh * 16] = *(const uint4*)src;
      *(uint4*)&As[sm * 40 + sh * 16 + 8] = *(const uint4*)(src + 8);
    }
#pragma unroll
    for (int it = 0; it < 2; ++it) {
      const int n = bn + it * 64;
      *(uint4*)&Bs[n * 40 + bc * 8] =
          *(const uint4*)&Ball[(size_t)(n0 + n) * 512 + kc * 32 + bc * 8];
    }
    __syncthreads();
    bf16x8 bfr[4], afr[4];
#pragma unroll
    for (int nf = 0; nf < 4; ++nf)
      bfr[nf] = *(const bf16x8*)&Bs[(wc * 64 + nf * 16 + col) * 40 + kg * 8];
#pragma unroll
    for (int mf = 0; mf < 4; ++mf)
      afr[mf] = *(const bf16x8*)&As[(wr * 64 + mf * 16 + col) * 40 + kg * 8];
#pragma unroll
    for (int nf = 0; nf < 4; ++nf)
#pragma unroll
      for (int mf = 0; mf < 4; ++mf)
        acc[nf][mf] = __builtin_amdgcn_mfma_f32_16x16x32_bf16(bfr[nf], afr[mf], acc[nf][mf], 0, 0, 0);
    __syncthreads();
  }
  // epilogue: s(m) = sum_n relu(c + b1[n]) * wp[n]; lane-local over 16 n's
#pragma unroll
  for (int mf = 0; mf < 4; ++mf) {
    float s = 0.f;
#pragma unroll
    for (int nf = 0; nf < 4; ++nf)
#pragma unroll
      for (int q = 0; q < 4; ++q) {
        const int nloc = wc * 64 + nf * 16 + kg * 4 + q;
        s += fmaxf(acc[nf][mf][q] + bs1[nloc], 0.f) * wps[nloc];
      }
    s += __shfl_xor(s, 16);
    s += __shfl_xor(s, 32);
    if (kg == 0) atomicAdd(&scores[m0 + wr * 64 + mf * 16 + col], s);
  }
}

// =====================================================================
// K8: pairwise SRL GEMM via BF16 MFMA. M=32768 N=512 K=512, tile 128x128.
// A built on the fly: bf16(relu(a_srl[span] + p_srl[pred] + srl_b0)).
// Swapped-operand mfma; epilogue: relu(+b1) x srl_wp (19) lane-local,
// 2-step kg shuffle reduce, atomicAdd into d_out (pre-init srl_bp).
// =====================================================================
__global__ __launch_bounds__(256) void k8_srl(const float* __restrict__ b1,
                                              const float* __restrict__ wp,
                                              const float* __restrict__ b0,
                                              float* __restrict__ ws,
                                              float* __restrict__ out) {
  __shared__ short As[128 * 40];
  __shared__ short Bs[128 * 40];
  __shared__ float wps20[128 * 20];   // wp rows padded 19->20 (col 19 = 0)
  __shared__ float bs1[128];
  const float* a_srl = ws + OFF_ASRL;
  const float* p_srl = ws + OFF_P_SRL;
  const unsigned short* Ball = (const unsigned short*)(ws + OFF_W1T_SRL);
  const int tid = threadIdx.x;
  const int m0 = blockIdx.x * 128, n0 = blockIdx.y * 128;
  for (int idx = tid; idx < 128 * 20; idx += 256) {
    int n = idx / 20, r = idx - n * 20;
    wps20[idx] = (r < 19) ? wp[(size_t)(n0 + n) * 19 + r] : 0.f;
  }
  if (tid < 128) bs1[tid] = b1[n0 + tid];
  const int lane = tid & 63, wv = tid >> 6;
  const int wr = wv >> 1, wc = wv & 1;
  const int col = lane & 15, kg = lane >> 4;
  const int sm = tid >> 1, sh = tid & 1;
  const int gm = m0 + sm;
  const float* arow = a_srl + (size_t)(gm >> 2) * 512;
  const float* prow = p_srl + (size_t)(((gm >> 12) << 2) | (gm & 3)) * 512;
  const int bn = tid >> 2, bc = tid & 3;
  f32x4 acc[4][4];
#pragma unroll
  for (int i = 0; i < 4; ++i)
#pragma unroll
    for (int j = 0; j < 4; ++j) {
      acc[i][j][0] = 0.f; acc[i][j][1] = 0.f; acc[i][j][2] = 0.f; acc[i][j][3] = 0.f;
    }

  for (int kc = 0; kc < 16; ++kc) {
    {
      const int kb = kc * 32 + sh * 16;
      unsigned uo[8];
#pragma unroll
      for (int q4 = 0; q4 < 4; ++q4) {
        float4 xa = *(const float4*)&arow[kb + q4 * 4];
        float4 xp = *(const float4*)&prow[kb + q4 * 4];
        float4 xb = *(const float4*)&b0[kb + q4 * 4];
        float v0 = fmaxf(xa.x + xp.x + xb.x, 0.f);
        float v1 = fmaxf(xa.y + xp.y + xb.y, 0.f);
        float v2 = fmaxf(xa.z + xp.z + xb.z, 0.f);
        float v3 = fmaxf(xa.w + xp.w + xb.w, 0.f);
        uo[q4 * 2 + 0] = (unsigned)f2bf(v0) | ((unsigned)f2bf(v1) << 16);
        uo[q4 * 2 + 1] = (unsigned)f2bf(v2) | ((unsigned)f2bf(v3) << 16);
      }
      uint4 w0 = {uo[0], uo[1], uo[2], uo[3]}, w1v = {uo[4], uo[5], uo[6], uo[7]};
      *(uint4*)&As[sm * 40 + sh * 16] = w0;
      *(uint4*)&As[sm * 40 + sh * 16 + 8] = w1v;
    }
#pragma unroll
    for (int it = 0; it < 2; ++it) {
      const int n = bn + it * 64;
      *(uint4*)&Bs[n * 40 + bc * 8] =
          *(const uint4*)&Ball[(size_t)(n0 + n) * 512 + kc * 32 + bc * 8];
    }
    __syncthreads();
    bf16x8 bfr[4], afr[4];
#pragma unroll
    for (int nf = 0; nf < 4; ++nf)
      bfr[nf] = *(const bf16x8*)&Bs[(wc * 64 + nf * 16 + col) * 40 + kg * 8];
#pragma unroll
    for (int mf = 0; mf < 4; ++mf)
      afr[mf] = *(const bf16x8*)&As[(wr * 64 + mf * 16 + col) * 40 + kg * 8];
#pragma unroll
    for (int nf = 0; nf < 4; ++nf)
#pragma unroll
      for (int mf = 0; mf < 4; ++mf)
        acc[nf][mf] = __builtin_amdgcn_mfma_f32_16x16x32_bf16(bfr[nf], afr[mf], acc[nf][mf], 0, 0, 0);
    __syncthreads();
  }
  // epilogue: pr[m][r] = sum_n relu(c + b1[n]) * wp[n][r]
  float pr[4][20];
#pragma unroll
  for (int mf = 0; mf < 4; ++mf)
#pragma unroll
    for (int r = 0; r < 20; ++r) pr[mf][r] = 0.f;
#pragma unroll
  for (int nf = 0; nf < 4; ++nf)
#pragma unroll
    for (int q = 0; q < 4; ++q) {
      const int nloc = wc * 64 + nf * 16 + kg * 4 + q;
      const float bb = bs1[nloc];
      float w4[20];
#pragma unroll
      for (int c = 0; c < 5; ++c) {
        float4 v = *(const float4*)&wps20[nloc * 20 + c * 4];
        w4[c * 4 + 0] = v.x; w4[c * 4 + 1] = v.y; w4[c * 4 + 2] = v.z; w4[c * 4 + 3] = v.w;
      }
#pragma unroll
      for (int mf = 0; mf < 4; ++mf) {
        const float val = fmaxf(acc[nf][mf][q] + bb, 0.f);
#pragma unroll
        for (int r = 0; r < 20; ++r) pr[mf][r] += val * w4[r];
      }
    }
#pragma unroll
  for (int mf = 0; mf < 4; ++mf) {
    const size_t row = (size_t)(m0 + wr * 64 + mf * 16 + col);
#pragma unroll
    for (int r = 0; r < 19; ++r) {
      float v = pr[mf][r];
      v += __shfl_xor(v, 16);
      v += __shfl_xor(v, 32);
      if (kg == 0) atomicAdd(&out[row * 19 + r], v);
    }
  }
}

// =====================================================================
// K9: finalize: add biaffine gathers + arg/pred scores, apply mask.
// =====================================================================
__global__ __launch_bounds__(128) void k9_fin(const int* __restrict__ slen,
                                              float* __restrict__ out,
                                              const float* __restrict__ ws) {
  const int sp = blockIdx.x, tid = threadIdx.x;
  if (tid >= G_ * R_) return;
  const int b = sp >> 10, s = sp & 1023;
  const int w = s >> 7, l = s & 127;
  const bool valid = (l + w) < slen[b];
  const int st = valid ? l : 0;
  const int en = valid ? l + w : 0;
  const int wd = en - st;
  const int g = tid / R_, r = tid % R_;
  const int p = b * G_ + g;
  const int pr = p * R_ + r;
  const size_t o = ((size_t)sp * G_ + g) * R_ + r;
  float val = out[o]
            + ws[OFF_MS + (size_t)pr * 128 + st]
            + ws[OFF_ME + (size_t)pr * 128 + en]
            + ws[OFF_MW + (size_t)pr * 8 + wd]
            + (ws[OFF_MHP + (size_t)pr * 129 + en + 1] - ws[OFF_MHP + (size_t)pr * 129 + st]) * 0.125f
            + ws[OFF_TC + pr]
            + ws[OFF_ARGS + sp]
            + ws[OFF_PSCORE + p];
  out[o] = valid ? val : 0.f;
}

// =====================================================================
extern "C" void kernel_launch(void* const* d_in, const int* in_sizes, int n_in,
                              void* d_out, int out_size, void* d_ws, size_t ws_size,
                              hipStream_t stream) {
  const float* hidden  = (const float*)d_in[0];
  const int*   slen    = (const int*)d_in[1];
  const int*   goldp   = (const int*)d_in[2];
  const float* wtab    = (const float*)d_in[3];
  const float* arg_w0  = (const float*)d_in[4];
  const float* arg_b0  = (const float*)d_in[5];
  const float* arg_w1  = (const float*)d_in[6];
  const float* arg_b1  = (const float*)d_in[7];
  const float* arg_wp  = (const float*)d_in[8];
  const float* arg_bp  = (const float*)d_in[9];
  const float* pred_w0 = (const float*)d_in[10];
  const float* pred_b0 = (const float*)d_in[11];
  const float* pred_w1 = (const float*)d_in[12];
  const float* pred_b1 = (const float*)d_in[13];
  const float* pred_wp = (const float*)d_in[14];
  const float* pred_bp = (const float*)d_in[15];
  const float* srl_w0  = (const float*)d_in[16];
  const float* srl_b0  = (const float*)d_in[17];
  const float* srl_w1  = (const float*)d_in[18];
  const float* srl_b1  = (const float*)d_in[19];
  const float* srl_wp  = (const float*)d_in[20];
  const float* srl_bp  = (const float*)d_in[21];
  const float* scale_w = (const float*)d_in[22];
  const float* scale_b = (const float*)d_in[23];
  const float* bw      = (const float*)d_in[24];
  float* out = (float*)d_out;
  float* ws  = (float*)d_ws;

  kw_cvt<<<dim3(8, 8, 2), 256, 0, stream>>>(arg_w1, srl_w1, ws);
  k1_proj<<<dim3(16, 24), 256, 0, stream>>>(hidden, arg_w0, srl_w0, ws);
  k2_prefix<<<32, 256, 0, stream>>>(ws);
  k3a_pred<<<32, 256, 0, stream>>>(hidden, goldp, pred_w0, pred_b0, pred_w1, pred_b1,
                                   pred_wp, pred_bp, srl_w0, ws);
  k3b_scale<<<NP_ * 7 + 2, 256, 0, stream>>>(hidden, goldp, scale_w, scale_b, wtab,
                                             arg_w0, srl_w0, ws);
  k4_t<<<(TM_ + 63) / 64, 256, 0, stream>>>(bw, ws);
  k5_biaff<<<NP_ * R_, 256, 0, stream>>>(hidden, wtab, ws);
  k6_span<<<NS_, 256, 0, stream>>>(slen, arg_b0, arg_bp, srl_bp, ws, out);
  k7_arg<<<dim3(64, 4), 256, 0, stream>>>(arg_b1, arg_wp, ws);
  k8_srl<<<dim3(256, 4), 256, 0, stream>>>(srl_b1, srl_wp, srl_b0, ws, out);
  k9_fin<<<NS_, 128, 0, stream>>>(slen, out, ws);
}

// Round 5
// 980.340 us; speedup vs baseline: 1.1755x; 1.1652x over previous
//
#include <hip/hip_runtime.h>

// ---------------- problem constants ----------------
constexpr int B_   = 8;
constexpr int L_   = 128;
constexpr int D_   = 512;
constexpr int MAW_ = 8;
constexpr int SWF_ = 20;
constexpr int FF_  = 512;
constexpr int R_   = 19;
constexpr int G_   = 4;
constexpr int SPAN_ = 3 * D_ + SWF_;   // 1556
constexpr int S1_   = SPAN_ + 1;       // 1557
constexpr int S_    = L_ * MAW_;       // 1024 spans / batch
constexpr int NS_   = B_ * S_;         // 8192 spans total
constexpr int NP_   = B_ * G_;         // 32 predicates
constexpr int TM_   = R_ * S1_;        // 29583 rows of biaffine_w
constexpr int M8_   = NS_ * G_;        // 32768 pairwise rows

// ---------------- workspace layout (float offsets) ----------------
constexpr size_t OFF_HS_ARG = 0;               // 6 x 1024x512 projections
constexpr size_t OFF_HE_ARG = 524288;
constexpr size_t OFF_HH_ARG = 1048576;
constexpr size_t OFF_HS_SRL = 1572864;
constexpr size_t OFF_HE_SRL = 2097152;
constexpr size_t OFF_HH_SRL = 2621440;
constexpr size_t OFF_PH_ARG = 3145728;         // 8 x 129 x 512 prefix
constexpr size_t OFF_PH_SRL = 3674112;
constexpr size_t OFF_P_SRL  = 4202496;         // 32 x 512
constexpr size_t OFF_PSCORE = 4218880;         // 32
constexpr size_t OFF_PRED1  = 4218912;         // 32 x 1557
constexpr size_t OFF_WD_ARG = 4268736;         // 8 x 512
constexpr size_t OFF_WD_SRL = 4272832;         // 8 x 512
constexpr size_t OFF_T      = 4276928;         // 32 x 29583  [p][r*1557+i]
constexpr size_t OFF_MS     = 5223584;         // 608 x 128
constexpr size_t OFF_ME     = 5301408;         // 608 x 128
constexpr size_t OFF_MHP    = 5379232;         // 608 x 129
constexpr size_t OFF_MW     = 5457664;         // 608 x 8
constexpr size_t OFF_TC     = 5462528;         // 608
constexpr size_t OFF_HARG   = 5463136;         // 8192 x 512 BF16
constexpr size_t OFF_W1T_ARG = 7560288;        // 512x512 bf16
constexpr size_t OFF_W1T_SRL = 7691360;        // 512x512 bf16
constexpr size_t OFF_ASRL   = 9657440;         // 8192 x 512 fp32
constexpr size_t OFF_ARGS   = 13851744;        // 8192 (unused now)
// Partial-sum slabs (reuse regions that are DEAD once k6 has run):
// k8 partials: 4 x 32768 x 20 floats = 2,621,440  -> fits in [0, OFF_PH_ARG)
constexpr size_t OFF_PART_SRL = 0;             // overlays HS/HE/HH_ARG (dead after k6)
// k7 partials: 4 x 8192 = 32,768 floats -> overlays PH_ARG (dead after k6)
constexpr size_t OFF_PART_ARG = 3145728;

typedef short bf16x8 __attribute__((ext_vector_type(8)));
typedef float f32x4  __attribute__((ext_vector_type(4)));

__device__ __forceinline__ unsigned short f2bf(float x) {
  unsigned u = __float_as_uint(x);
  unsigned r = (u + 0x7FFFu + ((u >> 16) & 1u)) >> 16;   // RNE
  return (unsigned short)r;
}

// =====================================================================
// K1: six per-token projections  Hx = hidden(1024x512) @ W(512x512)
// =====================================================================
__global__ __launch_bounds__(256) void k1_proj(const float* __restrict__ hidden,
                                               const float* __restrict__ arg_w0,
                                               const float* __restrict__ srl_w0,
                                               float* __restrict__ ws) {
  __shared__ float As[16][68];
  __shared__ float Bs[16][132];
  const int tid = threadIdx.x;
  const int m0 = blockIdx.x * 64;
  const int by = blockIdx.y;
  const int j = by >> 2;               // which projection 0..5
  const int c0 = (by & 3) * 128;       // col offset within projection
  const int rowoffs[3] = {0, 512, 1044};
  const float* W = (j < 3) ? (arg_w0 + (size_t)rowoffs[j] * FF_)
                           : (srl_w0 + (size_t)rowoffs[j - 3] * FF_);
  float* C = ws + (size_t)j * 524288;

  const int tx = tid & 15, ty = tid >> 4;
  float acc[4][8];
#pragma unroll
  for (int i = 0; i < 4; ++i)
#pragma unroll
    for (int jj = 0; jj < 8; ++jj) acc[i][jj] = 0.f;

  const int mlA = tid >> 2, kqA = (tid & 3) * 4;
  const int n4B = (tid & 31) * 4, krB = tid >> 5;

  for (int kc = 0; kc < 32; ++kc) {
    float4 av = *(const float4*)&hidden[(size_t)(m0 + mlA) * D_ + kc * 16 + kqA];
    As[kqA + 0][mlA] = av.x; As[kqA + 1][mlA] = av.y;
    As[kqA + 2][mlA] = av.z; As[kqA + 3][mlA] = av.w;
#pragma unroll
    for (int it = 0; it < 2; ++it) {
      int k = krB + it * 8;
      *(float4*)&Bs[k][n4B] = *(const float4*)&W[(size_t)(kc * 16 + k) * FF_ + c0 + n4B];
    }
    __syncthreads();
#pragma unroll
    for (int kk = 0; kk < 16; ++kk) {
      float4 a  = *(const float4*)&As[kk][ty * 4];
      float4 b0 = *(const float4*)&Bs[kk][tx * 8];
      float4 b1 = *(const float4*)&Bs[kk][tx * 8 + 4];
      float ar[4] = {a.x, a.y, a.z, a.w};
      float br[8] = {b0.x, b0.y, b0.z, b0.w, b1.x, b1.y, b1.z, b1.w};
#pragma unroll
      for (int i = 0; i < 4; ++i)
#pragma unroll
        for (int jj = 0; jj < 8; ++jj) acc[i][jj] += ar[i] * br[jj];
    }
    __syncthreads();
  }
#pragma unroll
  for (int i = 0; i < 4; ++i) {
    int row = m0 + ty * 4 + i;
    float4 o0 = {acc[i][0], acc[i][1], acc[i][2], acc[i][3]};
    float4 o1 = {acc[i][4], acc[i][5], acc[i][6], acc[i][7]};
    *(float4*)&C[(size_t)row * FF_ + c0 + tx * 8] = o0;
    *(float4*)&C[(size_t)row * FF_ + c0 + tx * 8 + 4] = o1;
  }
}

// =====================================================================
// KW: transpose + bf16-convert arg_w1 / srl_w1 -> w1T[n][k]
// =====================================================================
__global__ __launch_bounds__(256) void kw_cvt(const float* __restrict__ arg_w1,
                                              const float* __restrict__ srl_w1,
                                              float* __restrict__ ws) {
  __shared__ float tile[64][65];
  const int mat = blockIdx.z;
  const float* W = mat ? srl_w1 : arg_w1;
  unsigned short* T = (unsigned short*)(ws + (mat ? OFF_W1T_SRL : OFF_W1T_ARG));
  const int k0 = blockIdx.x * 64, n0 = blockIdx.y * 64;
  const int t = threadIdx.x;
  const int kk = t >> 4, nn = (t & 15) * 4;
#pragma unroll
  for (int it = 0; it < 4; ++it) {
    float4 v = *(const float4*)&W[(size_t)(k0 + kk + it * 16) * 512 + n0 + nn];
    tile[kk + it * 16][nn + 0] = v.x; tile[kk + it * 16][nn + 1] = v.y;
    tile[kk + it * 16][nn + 2] = v.z; tile[kk + it * 16][nn + 3] = v.w;
  }
  __syncthreads();
  const int n = t >> 2, kc = (t & 3) * 16;
  unsigned o[8];
#pragma unroll
  for (int j2 = 0; j2 < 8; ++j2) {
    unsigned lo = f2bf(tile[kc + 2 * j2][n]);
    unsigned hi = f2bf(tile[kc + 2 * j2 + 1][n]);
    o[j2] = lo | (hi << 16);
  }
  uint4 u0 = {o[0], o[1], o[2], o[3]}, u1 = {o[4], o[5], o[6], o[7]};
  unsigned short* dst = &T[(size_t)(n0 + n) * 512 + k0 + kc];
  *(uint4*)dst = u0;
  *(uint4*)(dst + 8) = u1;
}

// =====================================================================
// K2: prefix sums over L for the two head projections
// =====================================================================
__global__ __launch_bounds__(256) void k2_prefix(float* __restrict__ ws) {
  int idx = blockIdx.x * 256 + threadIdx.x;       // 0..8191
  int mat = idx >> 12;
  int b = (idx >> 9) & 7;
  int f = idx & 511;
  const float* src = ws + (mat == 0 ? OFF_HH_ARG : OFF_HH_SRL) + (size_t)(b * L_) * D_ + f;
  float* dst = ws + (mat == 0 ? OFF_PH_ARG : OFF_PH_SRL) + (size_t)(b * (L_ + 1)) * D_ + f;
  float run = 0.f;
  dst[0] = 0.f;
  for (int l = 0; l < L_; ++l) {
    run += src[(size_t)l * D_];
    dst[(size_t)(l + 1) * D_] = run;
  }
}

// =====================================================================
// K3a: predicate FFN + p_srl  (32 blocks, one per (b,g))
// =====================================================================
__global__ __launch_bounds__(256) void k3a_pred(const float* __restrict__ hidden,
                                                const int* __restrict__ goldp,
                                                const float* __restrict__ pw0, const float* __restrict__ pb0,
                                                const float* __restrict__ pw1, const float* __restrict__ pb1,
                                                const float* __restrict__ pwp, const float* __restrict__ pbp,
                                                const float* __restrict__ srl_w0,
                                                float* __restrict__ ws) {
  __shared__ float emb[512], h0[512], h1[512], red[256];
  const int p = blockIdx.x, tid = threadIdx.x;
  const int b = p >> 2;
  const int pi = goldp[p];
  const float* hrow = hidden + (size_t)(b * L_ + pi) * D_;
  emb[tid] = hrow[tid];
  emb[tid + 256] = hrow[tid + 256];
  __syncthreads();
#pragma unroll
  for (int h = 0; h < 2; ++h) {
    int f = tid + h * 256;
    float a = pb0[f];
    for (int d = 0; d < D_; ++d) a += emb[d] * pw0[(size_t)d * FF_ + f];
    h0[f] = fmaxf(a, 0.f);
  }
  __syncthreads();
#pragma unroll
  for (int h = 0; h < 2; ++h) {
    int f = tid + h * 256;
    float a = pb1[f];
    for (int d = 0; d < FF_; ++d) a += h0[d] * pw1[(size_t)d * FF_ + f];
    h1[f] = fmaxf(a, 0.f);
  }
  __syncthreads();
  red[tid] = h1[tid] * pwp[tid] + h1[tid + 256] * pwp[tid + 256];
  __syncthreads();
  for (int s = 128; s > 0; s >>= 1) {
    if (tid < s) red[tid] += red[tid + s];
    __syncthreads();
  }
  if (tid == 0) ws[OFF_PSCORE + p] = red[0] + pbp[0];
#pragma unroll
  for (int h = 0; h < 2; ++h) {
    int f = tid + h * 256;
    float a = 0.f;
    for (int d = 0; d < D_; ++d) a += emb[d] * srl_w0[(size_t)(SPAN_ + d) * FF_ + f];
    ws[OFF_P_SRL + (size_t)p * FF_ + f] = a;
  }
}

// =====================================================================
// K3b: pred_scaled -> pred1 (+ trailing 1), and the two width tables
// =====================================================================
__global__ __launch_bounds__(256) void k3b_scale(const float* __restrict__ hidden,
                                                 const int* __restrict__ goldp,
                                                 const float* __restrict__ scale_w,
                                                 const float* __restrict__ scale_b,
                                                 const float* __restrict__ wtab,
                                                 const float* __restrict__ arg_w0,
                                                 const float* __restrict__ srl_w0,
                                                 float* __restrict__ ws) {
  const int blk = blockIdx.x, tid = threadIdx.x;
  if (blk >= NP_ * 7) {
    int mat = blk - NP_ * 7;
    const float* W = (mat == 0 ? arg_w0 : srl_w0) + (size_t)(2 * D_) * FF_;
    float* dst = ws + (mat == 0 ? OFF_WD_ARG : OFF_WD_SRL);
    for (int idx = tid; idx < MAW_ * FF_; idx += 256) {
      int w = idx >> 9, f = idx & 511;
      float a = 0.f;
#pragma unroll
      for (int k = 0; k < SWF_; ++k) a += wtab[w * SWF_ + k] * W[(size_t)k * FF_ + f];
      dst[idx] = a;
    }
    return;
  }
  const int p = blk / 7, chunk = blk % 7;
  __shared__ float emb[512];
  const int b = p >> 2;
  const int pi = goldp[p];
  const float* hrow = hidden + (size_t)(b * L_ + pi) * D_;
  emb[tid] = hrow[tid];
  emb[tid + 256] = hrow[tid + 256];
  __syncthreads();
  const int i = chunk * 256 + tid;
  if (i < SPAN_) {
    float a = scale_b[i];
    for (int d = 0; d < D_; ++d) a += emb[d] * scale_w[(size_t)d * SPAN_ + i];
    ws[OFF_PRED1 + (size_t)p * S1_ + i] = fmaxf(a, 0.f);
  } else if (i == SPAN_) {
    ws[OFF_PRED1 + (size_t)p * S1_ + i] = 1.f;
  }
}

// =====================================================================
// K4: t[p][r*1557+i] = sum_j pred1[p][j] * bw[(r*1557+i)*1557 + j]
// =====================================================================
__global__ __launch_bounds__(256) void k4_t(const float* __restrict__ bw,
                                            float* __restrict__ ws) {
  __shared__ float As[32][65];
  __shared__ float Bs[32][36];
  const float* pred1 = ws + OFF_PRED1;
  float* t = ws + OFF_T;
  const int tid = threadIdx.x;
  const int m0 = blockIdx.x * 64;
  const int tx = tid & 7, ty = tid >> 3;
  float acc[2][4] = {{0.f, 0.f, 0.f, 0.f}, {0.f, 0.f, 0.f, 0.f}};
  const int mlA = tid >> 2, kqA = (tid & 3) * 8;
  const int pB = tid & 31, kqB = (tid >> 5) * 4;

  for (int kc = 0; kc < 49; ++kc) {
    const int j0 = kc * 32;
    {
      const int m = m0 + mlA;
      const bool mok = m < TM_;
      const float* arow = bw + (size_t)m * S1_ + j0 + kqA;
#pragma unroll
      for (int q = 0; q < 8; ++q) {
        int jj = j0 + kqA + q;
        As[kqA + q][mlA] = (mok && jj < S1_) ? arow[q] : 0.f;
      }
    }
    {
#pragma unroll
      for (int q = 0; q < 4; ++q) {
        int jj = j0 + kqB + q;
        Bs[kqB + q][pB] = (jj < S1_) ? pred1[(size_t)pB * S1_ + jj] : 0.f;
      }
    }
    __syncthreads();
#pragma unroll
    for (int kk = 0; kk < 32; ++kk) {
      float a0 = As[kk][ty * 2], a1 = As[kk][ty * 2 + 1];
      float4 bq = *(const float4*)&Bs[kk][tx * 4];
      acc[0][0] += a0 * bq.x; acc[0][1] += a0 * bq.y;
      acc[0][2] += a0 * bq.z; acc[0][3] += a0 * bq.w;
      acc[1][0] += a1 * bq.x; acc[1][1] += a1 * bq.y;
      acc[1][2] += a1 * bq.z; acc[1][3] += a1 * bq.w;
    }
    __syncthreads();
  }
#pragma unroll
  for (int i2 = 0; i2 < 2; ++i2) {
    int m = m0 + ty * 2 + i2;
    if (m < TM_) {
#pragma unroll
      for (int q = 0; q < 4; ++q) t[(size_t)(tx * 4 + q) * TM_ + m] = acc[i2][q];
    }
  }
}

// =====================================================================
// K5: biaffine gather tables: Ms/Me/Mhp/Mw/tconst per (p,r). 608 blocks.
// =====================================================================
__global__ __launch_bounds__(256) void k5_biaff(const float* __restrict__ hidden,
                                                const float* __restrict__ wtab,
                                                float* __restrict__ ws) {
  __shared__ float trow[S1_];
  __shared__ float mh[128];
  const int pr = blockIdx.x;
  const int p = pr / R_;
  const int b = p >> 2;
  const float* t = ws + OFF_T + (size_t)p * TM_ + (size_t)(pr % R_) * S1_;
  const int tid = threadIdx.x;
  for (int idx = tid; idx < S1_; idx += 256) trow[idx] = t[idx];
  __syncthreads();
  const int wv = tid >> 6, lane = tid & 63;
  const float* hb = hidden + (size_t)b * L_ * D_;
#pragma unroll
  for (int seg = 0; seg < 3; ++seg) {
    const int off = (seg == 0) ? 0 : (seg == 1) ? 512 : 1044;
    for (int l = wv * 32; l < wv * 32 + 32; ++l) {
      float part = 0.f;
#pragma unroll
      for (int q = 0; q < 8; ++q) {
        int d = q * 64 + lane;
        part += hb[(size_t)l * D_ + d] * trow[off + d];
      }
#pragma unroll
      for (int o = 32; o > 0; o >>= 1) part += __shfl_xor(part, o);
      if (lane == 0) {
        if (seg == 0) ws[OFF_MS + (size_t)pr * 128 + l] = part;
        else if (seg == 1) ws[OFF_ME + (size_t)pr * 128 + l] = part;
        else mh[l] = part;
      }
    }
  }
  __syncthreads();
  if (tid == 0) {
    float run = 0.f;
    float* Mhp = ws + OFF_MHP + (size_t)pr * 129;
    Mhp[0] = 0.f;
    for (int l = 0; l < 128; ++l) { run += mh[l]; Mhp[l + 1] = run; }
    ws[OFF_TC + pr] = trow[1556];
  }
  if (tid < MAW_) {
    float a = 0.f;
#pragma unroll
    for (int k = 0; k < SWF_; ++k) a += wtab[tid * SWF_ + k] * trow[1024 + k];
    ws[OFF_MW + (size_t)pr * 8 + tid] = a;
  }
}

// =====================================================================
// K6: assemble span-level layer-0 activations. HARG stored BF16.
// (no longer initializes d_out / ARGS — k9 is the sole out-writer)
// =====================================================================
__global__ __launch_bounds__(256) void k6_span(const int* __restrict__ slen,
                                               const float* __restrict__ arg_b0,
                                               float* __restrict__ ws) {
  const int sp = blockIdx.x, tid = threadIdx.x;
  const int b = sp >> 10, s = sp & 1023;
  const int w = s >> 7, l = s & 127;
  const bool valid = (l + w) < slen[b];
  const int st = valid ? l : 0;
  const int en = valid ? l + w : 0;
  const int wd = en - st;

  const float* HsA = ws + OFF_HS_ARG + (size_t)(b * 128 + st) * 512;
  const float* HeA = ws + OFF_HE_ARG + (size_t)(b * 128 + en) * 512;
  const float* PA1 = ws + OFF_PH_ARG + (size_t)(b * 129 + en + 1) * 512;
  const float* PA0 = ws + OFF_PH_ARG + (size_t)(b * 129 + st) * 512;
  const float* WdA = ws + OFF_WD_ARG + (size_t)wd * 512;
  const float* HsS = ws + OFF_HS_SRL + (size_t)(b * 128 + st) * 512;
  const float* HeS = ws + OFF_HE_SRL + (size_t)(b * 128 + en) * 512;
  const float* PS1 = ws + OFF_PH_SRL + (size_t)(b * 129 + en + 1) * 512;
  const float* PS0 = ws + OFF_PH_SRL + (size_t)(b * 129 + st) * 512;
  const float* WdS = ws + OFF_WD_SRL + (size_t)wd * 512;
  unsigned short* ha = (unsigned short*)(ws + OFF_HARG) + (size_t)sp * 512;
  float* as = ws + OFF_ASRL + (size_t)sp * 512;

#pragma unroll
  for (int h = 0; h < 2; ++h) {
    int f = tid + h * 256;
    float va = HsA[f] + HeA[f] + WdA[f] + (PA1[f] - PA0[f]) * 0.125f + arg_b0[f];
    ha[f] = f2bf(fmaxf(va, 0.f));
    as[f] = HsS[f] + HeS[f] + WdS[f] + (PS1[f] - PS0[f]) * 0.125f;
  }
}

// =====================================================================
// K7: arg FFN layer1 via BF16 MFMA. Partials to ws (NO atomics).
// =====================================================================
__global__ __launch_bounds__(256) void k7_arg(const float* __restrict__ b1,
                                              const float* __restrict__ wp,
                                              float* __restrict__ ws) {
  __shared__ short As[128 * 40];   // pitch 40 bf16 = 80 B -> even bank spread
  __shared__ short Bs[128 * 40];
  __shared__ float wps[128];
  __shared__ float bs1[128];
  const unsigned short* Aall = (const unsigned short*)(ws + OFF_HARG);
  const unsigned short* Ball = (const unsigned short*)(ws + OFF_W1T_ARG);
  float* part = ws + OFF_PART_ARG + (size_t)blockIdx.y * NS_;
  const int tid = threadIdx.x;
  const int m0 = blockIdx.x * 128, n0 = blockIdx.y * 128;
  if (tid < 128) { wps[tid] = wp[n0 + tid]; bs1[tid] = b1[n0 + tid]; }
  const int lane = tid & 63, wv = tid >> 6;
  const int wr = wv >> 1, wc = wv & 1;
  const int col = lane & 15, kg = lane >> 4;
  const int sm = tid >> 1, sh = tid & 1;
  const int bn = tid >> 2, bc = tid & 3;
  f32x4 acc[4][4];
#pragma unroll
  for (int i = 0; i < 4; ++i)
#pragma unroll
    for (int j = 0; j < 4; ++j) {
      acc[i][j][0] = 0.f; acc[i][j][1] = 0.f; acc[i][j][2] = 0.f; acc[i][j][3] = 0.f;
    }

  for (int kc = 0; kc < 16; ++kc) {
    {
      const unsigned short* src = &Aall[(size_t)(m0 + sm) * 512 + kc * 32 + sh * 16];
      *(uint4*)&As[sm * 40 + sh * 16] = *(const uint4*)src;
      *(uint4*)&As[sm * 40 + sh * 16 + 8] = *(const uint4*)(src + 8);
    }
#pragma unroll
    for (int it = 0; it < 2; ++it) {
      const int n = bn + it * 64;
      *(uint4*)&Bs[n * 40 + bc * 8] =
          *(const uint4*)&Ball[(size_t)(n0 + n) * 512 + kc * 32 + bc * 8];
    }
    __syncthreads();
    bf16x8 bfr[4], afr[4];
#pragma unroll
    for (int nf = 0; nf < 4; ++nf)
      bfr[nf] = *(const bf16x8*)&Bs[(wc * 64 + nf * 16 + col) * 40 + kg * 8];
#pragma unroll
    for (int mf = 0; mf < 4; ++mf)
      afr[mf] = *(const bf16x8*)&As[(wr * 64 + mf * 16 + col) * 40 + kg * 8];
#pragma unroll
    for (int nf = 0; nf < 4; ++nf)
#pragma unroll
      for (int mf = 0; mf < 4; ++mf)
        acc[nf][mf] = __builtin_amdgcn_mfma_f32_16x16x32_bf16(bfr[nf], afr[mf], acc[nf][mf], 0, 0, 0);
    __syncthreads();
  }
  // epilogue: s(m) = sum_n relu(c + b1[n]) * wp[n]; lane-local over 16 n's.
  // wc=0 and wc=1 waves cover different n-halves of the SAME rows -> LDS-combine.
  __shared__ float comb[2][128];
#pragma unroll
  for (int mf = 0; mf < 4; ++mf) {
    float s = 0.f;
#pragma unroll
    for (int nf = 0; nf < 4; ++nf)
#pragma unroll
      for (int q = 0; q < 4; ++q) {
        const int nloc = wc * 64 + nf * 16 + kg * 4 + q;
        s += fmaxf(acc[nf][mf][q] + bs1[nloc], 0.f) * wps[nloc];
      }
    s += __shfl_xor(s, 16);
    s += __shfl_xor(s, 32);
    if (kg == 0) comb[wc][wr * 64 + mf * 16 + col] = s;
  }
  __syncthreads();
  if (tid < 128) part[m0 + tid] = comb[0][tid] + comb[1][tid];
}

// =====================================================================
// K8: pairwise SRL GEMM via BF16 MFMA. Partials to ws (NO atomics).
// =====================================================================
__global__ __launch_bounds__(256) void k8_srl(const float* __restrict__ b1,
                                              const float* __restrict__ wp,
                                              const float* __restrict__ b0,
                                              float* __restrict__ ws) {
  __shared__ short As[128 * 40];
  __shared__ short Bs[128 * 40];
  __shared__ float wps20[128 * 20];   // wp rows padded 19->20 (col 19 = 0)
  __shared__ float bs1[128];
  const float* a_srl = ws + OFF_ASRL;
  const float* p_srl = ws + OFF_P_SRL;
  const unsigned short* Ball = (const unsigned short*)(ws + OFF_W1T_SRL);
  float* part = ws + OFF_PART_SRL + (size_t)blockIdx.y * ((size_t)M8_ * 20);
  const int tid = threadIdx.x;
  const int m0 = blockIdx.x * 128, n0 = blockIdx.y * 128;
  for (int idx = tid; idx < 128 * 20; idx += 256) {
    int n = idx / 20, r = idx - n * 20;
    wps20[idx] = (r < 19) ? wp[(size_t)(n0 + n) * 19 + r] : 0.f;
  }
  if (tid < 128) bs1[tid] = b1[n0 + tid];
  const int lane = tid & 63, wv = tid >> 6;
  const int wr = wv >> 1, wc = wv & 1;
  const int col = lane & 15, kg = lane >> 4;
  const int sm = tid >> 1, sh = tid & 1;
  const int gm = m0 + sm;
  const float* arow = a_srl + (size_t)(gm >> 2) * 512;
  const float* prow = p_srl + (size_t)(((gm >> 12) << 2) | (gm & 3)) * 512;
  const int bn = tid >> 2, bc = tid & 3;
  f32x4 acc[4][4];
#pragma unroll
  for (int i = 0; i < 4; ++i)
#pragma unroll
    for (int j = 0; j < 4; ++j) {
      acc[i][j][0] = 0.f; acc[i][j][1] = 0.f; acc[i][j][2] = 0.f; acc[i][j][3] = 0.f;
    }

  for (int kc = 0; kc < 16; ++kc) {
    {
      const int kb = kc * 32 + sh * 16;
      unsigned uo[8];
#pragma unroll
      for (int q4 = 0; q4 < 4; ++q4) {
        float4 xa = *(const float4*)&arow[kb + q4 * 4];
        float4 xp = *(const float4*)&prow[kb + q4 * 4];
        float4 xb = *(const float4*)&b0[kb + q4 * 4];
        float v0 = fmaxf(xa.x + xp.x + xb.x, 0.f);
        float v1 = fmaxf(xa.y + xp.y + xb.y, 0.f);
        float v2 = fmaxf(xa.z + xp.z + xb.z, 0.f);
        float v3 = fmaxf(xa.w + xp.w + xb.w, 0.f);
        uo[q4 * 2 + 0] = (unsigned)f2bf(v0) | ((unsigned)f2bf(v1) << 16);
        uo[q4 * 2 + 1] = (unsigned)f2bf(v2) | ((unsigned)f2bf(v3) << 16);
      }
      uint4 w0 = {uo[0], uo[1], uo[2], uo[3]}, w1v = {uo[4], uo[5], uo[6], uo[7]};
      *(uint4*)&As[sm * 40 + sh * 16] = w0;
      *(uint4*)&As[sm * 40 + sh * 16 + 8] = w1v;
    }
#pragma unroll
    for (int it = 0; it < 2; ++it) {
      const int n = bn + it * 64;
      *(uint4*)&Bs[n * 40 + bc * 8] =
          *(const uint4*)&Ball[(size_t)(n0 + n) * 512 + kc * 32 + bc * 8];
    }
    __syncthreads();
    bf16x8 bfr[4], afr[4];
#pragma unroll
    for (int nf = 0; nf < 4; ++nf)
      bfr[nf] = *(const bf16x8*)&Bs[(wc * 64 + nf * 16 + col) * 40 + kg * 8];
#pragma unroll
    for (int mf = 0; mf < 4; ++mf)
      afr[mf] = *(const bf16x8*)&As[(wr * 64 + mf * 16 + col) * 40 + kg * 8];
#pragma unroll
    for (int nf = 0; nf < 4; ++nf)
#pragma unroll
      for (int mf = 0; mf < 4; ++mf)
        acc[nf][mf] = __builtin_amdgcn_mfma_f32_16x16x32_bf16(bfr[nf], afr[mf], acc[nf][mf], 0, 0, 0);
    __syncthreads();
  }
  // epilogue: pr[m][r] = sum_n relu(c + b1[n]) * wp[n][r]
  float pr[4][20];
#pragma unroll
  for (int mf = 0; mf < 4; ++mf)
#pragma unroll
    for (int r = 0; r < 20; ++r) pr[mf][r] = 0.f;
#pragma unroll
  for (int nf = 0; nf < 4; ++nf)
#pragma unroll
    for (int q = 0; q < 4; ++q) {
      const int nloc = wc * 64 + nf * 16 + kg * 4 + q;
      const float bb = bs1[nloc];
      float w4[20];
#pragma unroll
      for (int c = 0; c < 5; ++c) {
        float4 v = *(const float4*)&wps20[nloc * 20 + c * 4];
        w4[c * 4 + 0] = v.x; w4[c * 4 + 1] = v.y; w4[c * 4 + 2] = v.z; w4[c * 4 + 3] = v.w;
      }
#pragma unroll
      for (int mf = 0; mf < 4; ++mf) {
        const float val = fmaxf(acc[nf][mf][q] + bb, 0.f);
#pragma unroll
        for (int r = 0; r < 20; ++r) pr[mf][r] += val * w4[r];
      }
    }
  // combine the two n-half waves (wc=0/1) for the same rows via LDS, then store
  __shared__ float comb[128 * 20];
#pragma unroll
  for (int mf = 0; mf < 4; ++mf) {
    const int rowl = wr * 64 + mf * 16 + col;
#pragma unroll
    for (int r = 0; r < 19; ++r) {
      float v = pr[mf][r];
      v += __shfl_xor(v, 16);
      v += __shfl_xor(v, 32);
      if (kg == 0 && wc == 0) comb[rowl * 20 + r] = v;
    }
  }
  __syncthreads();
#pragma unroll
  for (int mf = 0; mf < 4; ++mf) {
    const int rowl = wr * 64 + mf * 16 + col;
#pragma unroll
    for (int r = 0; r < 19; ++r) {
      float v = pr[mf][r];
      v += __shfl_xor(v, 16);
      v += __shfl_xor(v, 32);
      if (kg == 0 && wc == 1) comb[rowl * 20 + r] += v;
    }
  }
  __syncthreads();
  // coalesced store: 2560 floats (128 rows x 20)
  for (int idx = tid; idx < 128 * 20; idx += 256)
    part[((size_t)m0) * 20 + idx] = comb[idx];
}

// =====================================================================
// K9: finalize: sum partials + biaffine gathers + scores, apply mask.
// Sole writer of d_out.
// =====================================================================
__global__ __launch_bounds__(128) void k9_fin(const int* __restrict__ slen,
                                              const float* __restrict__ arg_bp,
                                              const float* __restrict__ srl_bp,
                                              float* __restrict__ out,
                                              const float* __restrict__ ws) {
  const int sp = blockIdx.x, tid = threadIdx.x;
  if (tid >= G_ * R_) return;
  const int b = sp >> 10, s = sp & 1023;
  const int w = s >> 7, l = s & 127;
  const bool valid = (l + w) < slen[b];
  const int st = valid ? l : 0;
  const int en = valid ? l + w : 0;
  const int wd = en - st;
  const int g = tid / R_, r = tid % R_;
  const int p = b * G_ + g;
  const int pr = p * R_ + r;
  const size_t row = (size_t)sp * G_ + g;
  const size_t o = row * R_ + r;
  float val = srl_bp[r];
#pragma unroll
  for (int y = 0; y < 4; ++y)
    val += ws[OFF_PART_SRL + (size_t)y * ((size_t)M8_ * 20) + row * 20 + r];
  float args = arg_bp[0];
#pragma unroll
  for (int y = 0; y < 4; ++y)
    args += ws[OFF_PART_ARG + (size_t)y * NS_ + sp];
  val += ws[OFF_MS + (size_t)pr * 128 + st]
       + ws[OFF_ME + (size_t)pr * 128 + en]
       + ws[OFF_MW + (size_t)pr * 8 + wd]
       + (ws[OFF_MHP + (size_t)pr * 129 + en + 1] - ws[OFF_MHP + (size_t)pr * 129 + st]) * 0.125f
       + ws[OFF_TC + pr]
       + args
       + ws[OFF_PSCORE + p];
  out[o] = valid ? val : 0.f;
}

// =====================================================================
extern "C" void kernel_launch(void* const* d_in, const int* in_sizes, int n_in,
                              void* d_out, int out_size, void* d_ws, size_t ws_size,
                              hipStream_t stream) {
  const float* hidden  = (const float*)d_in[0];
  const int*   slen    = (const int*)d_in[1];
  const int*   goldp   = (const int*)d_in[2];
  const float* wtab    = (const float*)d_in[3];
  const float* arg_w0  = (const float*)d_in[4];
  const float* arg_b0  = (const float*)d_in[5];
  const float* arg_w1  = (const float*)d_in[6];
  const float* arg_b1  = (const float*)d_in[7];
  const float* arg_wp  = (const float*)d_in[8];
  const float* arg_bp  = (const float*)d_in[9];
  const float* pred_w0 = (const float*)d_in[10];
  const float* pred_b0 = (const float*)d_in[11];
  const float* pred_w1 = (const float*)d_in[12];
  const float* pred_b1 = (const float*)d_in[13];
  const float* pred_wp = (const float*)d_in[14];
  const float* pred_bp = (const float*)d_in[15];
  const float* srl_w0  = (const float*)d_in[16];
  const float* srl_b0  = (const float*)d_in[17];
  const float* srl_w1  = (const float*)d_in[18];
  const float* srl_b1  = (const float*)d_in[19];
  const float* srl_wp  = (const float*)d_in[20];
  const float* srl_bp  = (const float*)d_in[21];
  const float* scale_w = (const float*)d_in[22];
  const float* scale_b = (const float*)d_in[23];
  const float* bw      = (const float*)d_in[24];
  float* out = (float*)d_out;
  float* ws  = (float*)d_ws;

  kw_cvt<<<dim3(8, 8, 2), 256, 0, stream>>>(arg_w1, srl_w1, ws);
  k1_proj<<<dim3(16, 24), 256, 0, stream>>>(hidden, arg_w0, srl_w0, ws);
  k2_prefix<<<32, 256, 0, stream>>>(ws);
  k3a_pred<<<32, 256, 0, stream>>>(hidden, goldp, pred_w0, pred_b0, pred_w1, pred_b1,
                                   pred_wp, pred_bp, srl_w0, ws);
  k3b_scale<<<NP_ * 7 + 2, 256, 0, stream>>>(hidden, goldp, scale_w, scale_b, wtab,
                                             arg_w0, srl_w0, ws);
  k4_t<<<(TM_ + 63) / 64, 256, 0, stream>>>(bw, ws);
  k5_biaff<<<NP_ * R_, 256, 0, stream>>>(hidden, wtab, ws);
  k6_span<<<NS_, 256, 0, stream>>>(slen, arg_b0, ws);
  k7_arg<<<dim3(64, 4), 256, 0, stream>>>(arg_b1, arg_wp, ws);
  k8_srl<<<dim3(256, 4), 256, 0, stream>>>(srl_b1, srl_wp, srl_b0, ws);
  k9_fin<<<NS_, 128, 0, stream>>>(slen, arg_bp, srl_bp, out, ws);
}